// Round 2
// baseline (882.224 us; speedup 1.0000x reference)
//
#include <hip/hip_runtime.h>

typedef unsigned short u16;

#define N_SP   3136     // 56*56
#define BNCOL  25088    // B * N_SP
#define NDIM   384
#define NINNER 512
#define SCALE_F 0.125f

__device__ __forceinline__ float bf2f(u16 u) {
  union { unsigned int i; float f; } v; v.i = ((unsigned int)u) << 16; return v.f;
}
__device__ __forceinline__ u16 f2bf(float f) {
  union { float f; unsigned int i; } v; v.f = f;
  unsigned int r = v.i + 0x7fffu + ((v.i >> 16) & 1u);   // RNE
  return (u16)(r >> 16);
}

// ---------- fused depthwise 3x3 conv + BN, both q and kv paths ----------
// x: (B, C, 56, 56) fp32 ; outputs yq/ykv in (C, B*N) layout, bf16
__global__ __launch_bounds__(256) void dwbn_kernel(
    const float* __restrict__ x,
    const float* __restrict__ qdw, const float* __restrict__ qg, const float* __restrict__ qb2,
    const float* __restrict__ qm,  const float* __restrict__ qv,
    const float* __restrict__ kdw, const float* __restrict__ kg, const float* __restrict__ kb2,
    const float* __restrict__ km,  const float* __restrict__ kvv,
    u16* __restrict__ yq, u16* __restrict__ ykv)
{
  int p = blockIdx.x * 256 + threadIdx.x;
  if (p >= N_SP) return;
  int c = blockIdx.y, bb = blockIdx.z;
  int h = p / 56, w = p - h * 56;
  const float* xp = x + ((size_t)bb * NDIM + c) * N_SP;
  float wq[9], wk[9];
#pragma unroll
  for (int i = 0; i < 9; ++i) { wq[i] = qdw[c*9+i]; wk[i] = kdw[c*9+i]; }
  float sq = 0.f, sk = 0.f;
#pragma unroll
  for (int dh = -1; dh <= 1; ++dh) {
    int hh = h + dh;
    if (hh < 0 || hh >= 56) continue;
#pragma unroll
    for (int dw2 = -1; dw2 <= 1; ++dw2) {
      int ww = w + dw2;
      if (ww < 0 || ww >= 56) continue;
      float xv = xp[hh*56 + ww];
      sq += xv * wq[(dh+1)*3 + (dw2+1)];
      sk += xv * wk[(dh+1)*3 + (dw2+1)];
    }
  }
  float invq = qg[c] * rsqrtf(qv[c] + 1e-5f);
  float oq = sq * invq + (qb2[c] - qm[c] * invq);
  float invk = kg[c] * rsqrtf(kvv[c] + 1e-5f);
  float ok = sk * invk + (kb2[c] - km[c] * invk);
  size_t o = (size_t)c * BNCOL + (size_t)bb * N_SP + p;
  yq[o]  = f2bf(oq);
  ykv[o] = f2bf(ok);
}

// ---------- generic GEMM: C(MxBNCOL) = A(MxKd,fp32) * B(KdxBNCOL,bf16) ----------
// mode 0: store bf16 C (C,BN layout). mode 1: +bias, scatter fp32 to NCHW d_out.
__global__ __launch_bounds__(256) void gemm_kernel(
    const float* __restrict__ A, const u16* __restrict__ B, u16* __restrict__ C,
    int M, int Kd, int mode, const float* __restrict__ bias, float* __restrict__ Out)
{
  __shared__ float As[64][20];   // [m][k], row padded to 20 floats (16B-aligned rows)
  __shared__ float Bs[16][64];   // [k][n]
  int tid = threadIdx.x;
  int tx = tid & 15, ty = tid >> 4;
  int tx4 = tx * 4, ty4 = ty * 4;
  int m0 = blockIdx.y * 64, c0 = blockIdx.x * 64;
  int arow = tid >> 2, aq = tid & 3;
  const float* Ap = A + (size_t)(m0 + arow) * Kd + aq * 4;
  const u16* Bp = B + (size_t)ty * BNCOL + c0 + tx4;
  float acc[4][4] = {{0.f}};
  for (int k0 = 0; k0 < Kd; k0 += 16) {
    float4 af = *(const float4*)(Ap + k0);
    ushort4 b4 = *(const ushort4*)(Bp + (size_t)k0 * BNCOL);
    float4 bf_; bf_.x = bf2f(b4.x); bf_.y = bf2f(b4.y); bf_.z = bf2f(b4.z); bf_.w = bf2f(b4.w);
    *(float4*)&As[arow][aq * 4] = af;
    *(float4*)&Bs[ty][tx4] = bf_;
    __syncthreads();
#pragma unroll
    for (int kk4 = 0; kk4 < 4; ++kk4) {
      float4 av[4], bv[4];
#pragma unroll
      for (int i = 0; i < 4; ++i) av[i] = *(const float4*)&As[ty4 + i][kk4 * 4];
#pragma unroll
      for (int k = 0; k < 4; ++k) bv[k] = *(const float4*)&Bs[kk4 * 4 + k][tx4];
#pragma unroll
      for (int i = 0; i < 4; ++i) {
        const float* ai = (const float*)&av[i];
#pragma unroll
        for (int k = 0; k < 4; ++k) {
          float aa = ai[k];
          acc[i][0] += aa * bv[k].x;
          acc[i][1] += aa * bv[k].y;
          acc[i][2] += aa * bv[k].z;
          acc[i][3] += aa * bv[k].w;
        }
      }
    }
    __syncthreads();
  }
  if (mode == 0) {
#pragma unroll
    for (int i = 0; i < 4; ++i) {
      int row = m0 + ty4 + i;
      ushort4 o;
      o.x = f2bf(acc[i][0]); o.y = f2bf(acc[i][1]);
      o.z = f2bf(acc[i][2]); o.w = f2bf(acc[i][3]);
      *(ushort4*)(C + (size_t)row * BNCOL + c0 + tx4) = o;
    }
  } else {
    int col = c0 + tx4;
    int bb = col / N_SP;           // N_SP = 49*64, tiles never straddle batches
    int pp = col - bb * N_SP;
#pragma unroll
    for (int i = 0; i < 4; ++i) {
      int row = m0 + ty4 + i;
      float bi = bias[row];
      float4 o;
      o.x = acc[i][0] + bi; o.y = acc[i][1] + bi;
      o.z = acc[i][2] + bi; o.w = acc[i][3] + bi;
      *(float4*)(Out + ((size_t)bb * NDIM + row) * N_SP + pp) = o;
    }
  }
}

// ---------- diag = SCALE * sum_d q*k ; m0 = sum(diag) ----------
__global__ __launch_bounds__(256) void diag_kernel(
    const u16* __restrict__ Q, const u16* __restrict__ KVb,
    float* __restrict__ dg, float* __restrict__ m0)
{
  int bh = blockIdx.y, bb = bh >> 3, h = bh & 7;
  int p = blockIdx.x * 256 + threadIdx.x;
  float s = 0.f;
  if (p < N_SP) {
    size_t base = (size_t)(h * 64) * BNCOL + (size_t)bb * N_SP + p;
    const u16* qp = Q + base;
    const u16* kp = KVb + base;   // k = first NINNER rows of KV
#pragma unroll 8
    for (int d = 0; d < 64; ++d)
      s += bf2f(qp[(size_t)d * BNCOL]) * bf2f(kp[(size_t)d * BNCOL]);
    s *= SCALE_F;
    dg[bh * N_SP + p] = s;
  }
  float r = (p < N_SP) ? s : 0.f;
#pragma unroll
  for (int off = 32; off > 0; off >>= 1) r += __shfl_down(r, off);
  __shared__ float wsum[4];
  int lane = threadIdx.x & 63, wv = threadIdx.x >> 6;
  if (lane == 0) wsum[wv] = r;
  __syncthreads();
  if (threadIdx.x == 0) atomicAdd(m0, wsum[0] + wsum[1] + wsum[2] + wsum[3]);
}

// ---------- ktv[bh,d,e] = sum_p k[p,d] v[p,e] (p-split x7, fp32 atomics) ----------
__global__ __launch_bounds__(256) void ktv_kernel(
    const u16* __restrict__ KVb, float* __restrict__ ktv)
{
  int bh = blockIdx.y, bb = bh >> 3, h = bh & 7;
  __shared__ float Ks[64][65];
  __shared__ float Vs[64][65];
  int tid = threadIdx.x;
  int tx = tid & 15, ty = tid >> 4;
  float acc[4][4] = {{0.f}};
  for (int ch = 0; ch < 7; ++ch) {
    int p0 = blockIdx.x * 448 + ch * 64;
    size_t base = (size_t)bb * N_SP + p0;
    for (int l = tid; l < 4096; l += 256) {
      int d = l >> 6, pp = l & 63;
      Ks[d][pp] = bf2f(KVb[(size_t)(h*64 + d) * BNCOL + base + pp]);
      Vs[d][pp] = bf2f(KVb[(size_t)(NINNER + h*64 + d) * BNCOL + base + pp]);
    }
    __syncthreads();
#pragma unroll 4
    for (int pp = 0; pp < 64; ++pp) {
      float kk[4], vv[4];
#pragma unroll
      for (int i = 0; i < 4; ++i) kk[i] = Ks[ty*4 + i][pp];
#pragma unroll
      for (int j = 0; j < 4; ++j) vv[j] = Vs[tx*4 + j][pp];
#pragma unroll
      for (int i = 0; i < 4; ++i)
#pragma unroll
        for (int j = 0; j < 4; ++j) acc[i][j] += kk[i] * vv[j];
    }
    __syncthreads();
  }
  float* kt = ktv + bh * 4096;
#pragma unroll
  for (int i = 0; i < 4; ++i)
#pragma unroll
    for (int j = 0; j < 4; ++j)
      atomicAdd(&kt[(ty*4 + i) * 64 + tx*4 + j], acc[i][j]);
}

// ---------- out[p,e] = (m0 - diag[p])*v[p,e] + SCALE * sum_d q[p,d]*ktv[d,e] ----------
__global__ __launch_bounds__(256) void attn_out_kernel(
    const u16* __restrict__ Q, const u16* __restrict__ KVb,
    const float* __restrict__ dg, const float* __restrict__ ktv,
    const float* __restrict__ m0p, u16* __restrict__ OutA)
{
  int bh = blockIdx.y, bb = bh >> 3, h = bh & 7;
  int p0 = blockIdx.x * 64;
  __shared__ float Kt[64][68];   // [d][e]
  __shared__ float Qs[64][68];   // [d][pp]
  __shared__ float Vs[64][68];   // [e][pp]
  __shared__ float ds_[64];
  int tid = threadIdx.x;
  const float* kt = ktv + bh * 4096;
  for (int l = tid; l < 4096; l += 256) Kt[l >> 6][l & 63] = kt[l];
  size_t base = (size_t)bb * N_SP + p0;
  for (int l = tid; l < 4096; l += 256) {
    int d = l >> 6, pp = l & 63;
    Qs[d][pp] = bf2f(Q[(size_t)(h*64 + d) * BNCOL + base + pp]);
    Vs[d][pp] = bf2f(KVb[(size_t)(NINNER + h*64 + d) * BNCOL + base + pp]);
  }
  if (tid < 64) ds_[tid] = dg[bh * N_SP + p0 + tid];
  __syncthreads();
  float m0v = *m0p;
  int tx = tid & 15, ty = tid >> 4;
  int e0 = tx * 4, pq = ty * 4;
  float acc[4][4] = {{0.f}};   // [pi][ej]
#pragma unroll 8
  for (int d = 0; d < 64; ++d) {
    float4 qv  = *(const float4*)&Qs[d][pq];
    float4 kv4 = *(const float4*)&Kt[d][e0];
    const float* q_ = (const float*)&qv;
#pragma unroll
    for (int pi = 0; pi < 4; ++pi) {
      acc[pi][0] += q_[pi] * kv4.x;
      acc[pi][1] += q_[pi] * kv4.y;
      acc[pi][2] += q_[pi] * kv4.z;
      acc[pi][3] += q_[pi] * kv4.w;
    }
  }
#pragma unroll
  for (int ej = 0; ej < 4; ++ej) {
    int e = e0 + ej;
    float o_[4];
#pragma unroll
    for (int pi = 0; pi < 4; ++pi) {
      float vv = Vs[e][pq + pi];
      o_[pi] = SCALE_F * acc[pi][ej] + (m0v - ds_[pq + pi]) * vv;
    }
    ushort4 ov;
    ov.x = f2bf(o_[0]); ov.y = f2bf(o_[1]); ov.z = f2bf(o_[2]); ov.w = f2bf(o_[3]);
    *(ushort4*)(OutA + (size_t)(h*64 + e) * BNCOL + base + pq) = ov;
  }
}

extern "C" void kernel_launch(void* const* d_in, const int* in_sizes, int n_in,
                              void* d_out, int out_size, void* d_ws, size_t ws_size,
                              hipStream_t stream)
{
  (void)in_sizes; (void)n_in; (void)out_size; (void)ws_size;
  const float* x      = (const float*)d_in[0];
  const float* wq_dw  = (const float*)d_in[1];
  const float* wq_g   = (const float*)d_in[2];
  const float* wq_b   = (const float*)d_in[3];
  const float* wq_m   = (const float*)d_in[4];
  const float* wq_v   = (const float*)d_in[5];
  const float* wq_pw  = (const float*)d_in[6];
  const float* wkv_dw = (const float*)d_in[7];
  const float* wkv_g  = (const float*)d_in[8];
  const float* wkv_b  = (const float*)d_in[9];
  const float* wkv_m  = (const float*)d_in[10];
  const float* wkv_v  = (const float*)d_in[11];
  const float* wkv_pw = (const float*)d_in[12];
  const float* wo     = (const float*)d_in[13];
  const float* bo     = (const float*)d_in[14];
  float* out = (float*)d_out;

  char* ws = (char*)d_ws;
  size_t off = 0;
  auto alloc = [&](size_t bytes) {
    void* p = ws + off; off = (off + bytes + 255) & ~(size_t)255; return p;
  };
  u16* yq   = (u16*)alloc((size_t)NDIM * BNCOL * 2);        // 19.27 MB
  u16* ykv  = (u16*)alloc((size_t)NDIM * BNCOL * 2);        // 19.27 MB
  u16* Qb   = (u16*)alloc((size_t)NINNER * BNCOL * 2);      // 25.69 MB
  u16* KVb  = (u16*)alloc((size_t)2 * NINNER * BNCOL * 2);  // 51.38 MB
  float* dgb  = (float*)alloc((size_t)64 * N_SP * 4);       // 0.80 MB
  float* ktvb = (float*)alloc((size_t)64 * 4096 * 4 + 64);  // 1.05 MB (+m0 tail)
  float* m0 = ktvb + 64 * 4096;
  u16* OutA = yq;   // alias: yq/ykv dead after the pw GEMMs; 25.7 MB fits in their 38.5 MB

  // zero ktv accumulators + m0 scalar (ws is poisoned 0xAA before every call)
  hipMemsetAsync(ktvb, 0, (size_t)64 * 4096 * 4 + 4, stream);

  dwbn_kernel<<<dim3(13, NDIM, 8), 256, 0, stream>>>(
      x, wq_dw, wq_g, wq_b, wq_m, wq_v,
      wkv_dw, wkv_g, wkv_b, wkv_m, wkv_v, yq, ykv);

  gemm_kernel<<<dim3(392, 8), 256, 0, stream>>>(wq_pw, yq, Qb, 512, 384, 0, nullptr, nullptr);
  gemm_kernel<<<dim3(392, 16), 256, 0, stream>>>(wkv_pw, ykv, KVb, 1024, 384, 0, nullptr, nullptr);

  diag_kernel<<<dim3(13, 64), 256, 0, stream>>>(Qb, KVb, dgb, m0);
  ktv_kernel<<<dim3(7, 64), 256, 0, stream>>>(KVb, ktvb);
  attn_out_kernel<<<dim3(49, 64), 256, 0, stream>>>(Qb, KVb, dgb, ktvb, m0, OutA);

  gemm_kernel<<<dim3(392, 6), 256, 0, stream>>>(wo, OutA, nullptr, 384, 512, 1, bo, out);
}

// Round 3
// 426.029 us; speedup vs baseline: 2.0708x; 2.0708x over previous
//
#include <hip/hip_runtime.h>

typedef unsigned short u16;

#define N_SP   3136     // 56*56
#define BNCOL  25088    // B * N_SP
#define NDIM   384
#define NINNER 512
#define SCALE_F 0.125f

typedef __attribute__((ext_vector_type(8))) short bf16x8;
typedef __attribute__((ext_vector_type(4))) float f32x4;

#define AS1 __attribute__((address_space(1)))
#define AS3 __attribute__((address_space(3)))

__device__ __forceinline__ float bf2f(u16 u) {
  union { unsigned int i; float f; } v; v.i = ((unsigned int)u) << 16; return v.f;
}
__device__ __forceinline__ u16 f2bf(float f) {
  union { float f; unsigned int i; } v; v.f = f;
  unsigned int r = v.i + 0x7fffu + ((v.i >> 16) & 1u);   // RNE
  return (u16)(r >> 16);
}

// async global->LDS, 16B per lane. lds base must be wave-uniform; lane i lands at lds + i*16B.
__device__ __forceinline__ void g2l16(const u16* g, u16* l) {
  __builtin_amdgcn_global_load_lds((const AS1 unsigned int*)g,
                                   (AS3 unsigned int*)l, 16, 0, 0);
}

// ---------- weight fp32 -> bf16 convert (wq_pw 512x384, wkv_pw 1024x384, wo 384x512) ----------
__global__ __launch_bounds__(256) void cvt_kernel(
    const float* __restrict__ a, const float* __restrict__ b, const float* __restrict__ c,
    u16* __restrict__ oa, u16* __restrict__ ob, u16* __restrict__ oc)
{
  int i = blockIdx.x * 256 + threadIdx.x;
  if (i < 196608) oa[i] = f2bf(a[i]);
  ob[i] = f2bf(b[i]);               // grid sized exactly to 393216
  if (i < 196608) oc[i] = f2bf(c[i]);
}

// ---------- fused depthwise 3x3 conv + BN (q and kv paths), output (BN, C) bf16 ----------
// tile: 64 positions x 32 channels, LDS transpose for coalesced (bn,c) stores
__global__ __launch_bounds__(256) void dwbn_kernel(
    const float* __restrict__ x,
    const float* __restrict__ qdw, const float* __restrict__ qg, const float* __restrict__ qb2,
    const float* __restrict__ qm,  const float* __restrict__ qv,
    const float* __restrict__ kdw, const float* __restrict__ kg, const float* __restrict__ kb2,
    const float* __restrict__ km,  const float* __restrict__ kvv,
    u16* __restrict__ yq, u16* __restrict__ ykv)
{
  __shared__ u16 Lq[64][40];
  __shared__ u16 Lk[64][40];
  int tid = threadIdx.x;
  int bb = blockIdx.z, c0 = blockIdx.y * 32, p0 = blockIdx.x * 64;
  int pl = tid & 63, cg = tid >> 6;
  int p = p0 + pl;
  int h = p / 56, w = p - h * 56;
  __attribute__((aligned(16))) u16 oq[8];
  __attribute__((aligned(16))) u16 ok[8];
#pragma unroll
  for (int i = 0; i < 8; ++i) {
    int c = c0 + cg * 8 + i;
    const float* xp = x + ((size_t)bb * NDIM + c) * N_SP;
    const float* wqp = qdw + c * 9;
    const float* wkp = kdw + c * 9;
    float sq = 0.f, sk = 0.f;
#pragma unroll
    for (int dh = -1; dh <= 1; ++dh) {
      int hh = h + dh;
      if (hh < 0 || hh >= 56) continue;
#pragma unroll
      for (int dw2 = -1; dw2 <= 1; ++dw2) {
        int ww = w + dw2;
        if (ww < 0 || ww >= 56) continue;
        float xv = xp[hh * 56 + ww];
        sq += xv * wqp[(dh + 1) * 3 + dw2 + 1];
        sk += xv * wkp[(dh + 1) * 3 + dw2 + 1];
      }
    }
    float invq = qg[c] * rsqrtf(qv[c] + 1e-5f);
    float invk = kg[c] * rsqrtf(kvv[c] + 1e-5f);
    oq[i] = f2bf(sq * invq + (qb2[c] - qm[c] * invq));
    ok[i] = f2bf(sk * invk + (kb2[c] - km[c] * invk));
  }
  *(ushort4*)&Lq[pl][cg * 8]     = *(ushort4*)&oq[0];
  *(ushort4*)&Lq[pl][cg * 8 + 4] = *(ushort4*)&oq[4];
  *(ushort4*)&Lk[pl][cg * 8]     = *(ushort4*)&ok[0];
  *(ushort4*)&Lk[pl][cg * 8 + 4] = *(ushort4*)&ok[4];
  __syncthreads();
  int pr = tid >> 2, cc = (tid & 3) * 8;
  size_t g = ((size_t)bb * N_SP + p0 + pr) * NDIM + c0 + cc;
  *(ushort4*)(yq + g)      = *(ushort4*)&Lq[pr][cc];
  *(ushort4*)(yq + g + 4)  = *(ushort4*)&Lq[pr][cc + 4];
  *(ushort4*)(ykv + g)     = *(ushort4*)&Lk[pr][cc];
  *(ushort4*)(ykv + g + 4) = *(ushort4*)&Lk[pr][cc + 4];
}

// ---------- MFMA GEMM: D[m][n] = sum_k W[m][k] * Act[n][k]  (NT form) ----------
// W: bf16 M x Kd row-major. Act: bf16 BN x Kd row-major (row stride == Kd).
// mode 0: transpose-store bf16 to Cout (BN x Cstride) at column m.
// mode 1: +bias, scatter fp32 to (B, 384, 3136) NCHW output.
__global__ __launch_bounds__(256) void mfma_gemm(
    const u16* __restrict__ W, const u16* __restrict__ Act, int Kd,
    u16* __restrict__ Cout, int Cstride,
    int mode, const float* __restrict__ bias, float* __restrict__ Out)
{
  __shared__ union {
    struct { u16 A[128 * 32]; u16 B[128 * 32]; } s;   // [row][k] 8KB each
    u16 T[128 * 132];                                  // epilogue transpose [n][m]
  } lds;
  int tid = threadIdx.x;
  int lane = tid & 63, wv = tid >> 6;
  int wm = (wv >> 1) * 64, wn = (wv & 1) * 64;
  int m0 = blockIdx.y * 128, n0 = blockIdx.x * 128;
  int srow = lane >> 2;          // 0..15
  int sch = (lane & 3) * 8;      // k chunk
  int arow0 = wv * 32;           // each wave stages 32 rows of A and B
  const u16* Wg   = W   + (size_t)(m0 + arow0 + srow) * Kd + sch;
  const u16* Actg = Act + (size_t)(n0 + arow0 + srow) * Kd + sch;
  u16* Al = &lds.s.A[arow0 * 32];
  u16* Bl = &lds.s.B[arow0 * 32];
  f32x4 acc[4][4];
#pragma unroll
  for (int i = 0; i < 4; ++i)
#pragma unroll
    for (int j = 0; j < 4; ++j) acc[i][j] = (f32x4){0.f, 0.f, 0.f, 0.f};

  int ml = lane & 15, q8 = (lane >> 4) * 8;
  for (int k0 = 0; k0 < Kd; k0 += 32) {
    g2l16(Wg + k0, Al);
    g2l16(Wg + k0 + (size_t)16 * Kd, Al + 16 * 32);
    g2l16(Actg + k0, Bl);
    g2l16(Actg + k0 + (size_t)16 * Kd, Bl + 16 * 32);
    __syncthreads();
    bf16x8 af[4], bfr[4];
#pragma unroll
    for (int i = 0; i < 4; ++i) {
      af[i]  = *(const bf16x8*)&lds.s.A[(wm + i * 16 + ml) * 32 + q8];
      bfr[i] = *(const bf16x8*)&lds.s.B[(wn + i * 16 + ml) * 32 + q8];
    }
#pragma unroll
    for (int i = 0; i < 4; ++i)
#pragma unroll
      for (int j = 0; j < 4; ++j)
        acc[i][j] = __builtin_amdgcn_mfma_f32_16x16x32_bf16(af[i], bfr[j], acc[i][j], 0, 0, 0);
    __syncthreads();
  }

  if (mode == 0) {
    int q4 = (lane >> 4) * 4;
#pragma unroll
    for (int i = 0; i < 4; ++i)
#pragma unroll
      for (int j = 0; j < 4; ++j) {
        int n = wn + j * 16 + ml;
        int m = wm + i * 16 + q4;
        ushort4 o;
        o.x = f2bf(acc[i][j][0]); o.y = f2bf(acc[i][j][1]);
        o.z = f2bf(acc[i][j][2]); o.w = f2bf(acc[i][j][3]);
        *(ushort4*)&lds.T[n * 132 + m] = o;   // T[n][m..m+3]
      }
    __syncthreads();
#pragma unroll
    for (int it = 0; it < 8; ++it) {
      int n = it * 16 + (tid >> 4);
      int mc = (tid & 15) * 8;
      ushort4 a = *(ushort4*)&lds.T[n * 132 + mc];
      ushort4 b = *(ushort4*)&lds.T[n * 132 + mc + 4];
      u16* gp = Cout + (size_t)(n0 + n) * Cstride + m0 + mc;
      *(ushort4*)gp = a;
      *(ushort4*)(gp + 4) = b;
    }
  } else {
    int q4 = (lane >> 4) * 4;
#pragma unroll
    for (int i = 0; i < 4; ++i)
#pragma unroll
      for (int j = 0; j < 4; ++j) {
        int n = n0 + wn + j * 16 + ml;
        int bb = n / N_SP, p = n - bb * N_SP;
#pragma unroll
        for (int r = 0; r < 4; ++r) {
          int m = m0 + wm + i * 16 + q4 + r;
          Out[((size_t)bb * NDIM + m) * N_SP + p] = acc[i][j][r] + bias[m];
        }
      }
  }
}

// ---------- diag[bn][h] = SCALE * sum_d q.k ; m0 = sum ----------
__global__ __launch_bounds__(256) void diag_kernel(
    const u16* __restrict__ Q, const u16* __restrict__ KV,
    float* __restrict__ dg, float* __restrict__ m0)
{
  int t = blockIdx.x * 256 + threadIdx.x;
  int bn = t >> 3, hh = t & 7;
  const u16* qp = Q + (size_t)bn * NINNER + hh * 64;
  const u16* kp = KV + (size_t)bn * (2 * NINNER) + hh * 64;
  float s = 0.f;
#pragma unroll
  for (int j = 0; j < 16; ++j) {
    ushort4 a = *(const ushort4*)(qp + 4 * j);
    ushort4 b = *(const ushort4*)(kp + 4 * j);
    s += bf2f(a.x) * bf2f(b.x) + bf2f(a.y) * bf2f(b.y)
       + bf2f(a.z) * bf2f(b.z) + bf2f(a.w) * bf2f(b.w);
  }
  s *= SCALE_F;
  dg[t] = s;
  float r = s;
#pragma unroll
  for (int off = 32; off > 0; off >>= 1) r += __shfl_down(r, off);
  __shared__ float wsum[4];
  if ((threadIdx.x & 63) == 0) wsum[threadIdx.x >> 6] = r;
  __syncthreads();
  if (threadIdx.x == 0) atomicAdd(m0, wsum[0] + wsum[1] + wsum[2] + wsum[3]);
}

// ---------- ktv[bh][d][e] = sum_p k[p][d] v[p][e]  (p-split x7, fp32 atomics) ----------
__global__ __launch_bounds__(256) void ktv_kernel(
    const u16* __restrict__ KV, float* __restrict__ ktv)
{
  int bh = blockIdx.y, bb = bh >> 3, hh = bh & 7;
  __shared__ float Ks[64][68];   // [pp][d]
  __shared__ float Vs[64][68];   // [pp][e]
  int tid = threadIdx.x, tx = tid & 15, ty = tid >> 4;
  float acc[4][4] = {{0.f}};
  for (int ch = 0; ch < 7; ++ch) {
    int p0 = blockIdx.x * 448 + ch * 64;
    __syncthreads();
    for (int l = tid; l < 512; l += 256) {
      int pp = l >> 3, c8 = (l & 7) * 8;
      const u16* row = KV + ((size_t)bb * N_SP + p0 + pp) * (2 * NINNER) + hh * 64 + c8;
      ushort4 k1 = *(const ushort4*)row, k2 = *(const ushort4*)(row + 4);
      ushort4 v1 = *(const ushort4*)(row + NINNER), v2 = *(const ushort4*)(row + NINNER + 4);
      float4 fk1 = {bf2f(k1.x), bf2f(k1.y), bf2f(k1.z), bf2f(k1.w)};
      float4 fk2 = {bf2f(k2.x), bf2f(k2.y), bf2f(k2.z), bf2f(k2.w)};
      float4 fv1 = {bf2f(v1.x), bf2f(v1.y), bf2f(v1.z), bf2f(v1.w)};
      float4 fv2 = {bf2f(v2.x), bf2f(v2.y), bf2f(v2.z), bf2f(v2.w)};
      *(float4*)&Ks[pp][c8] = fk1; *(float4*)&Ks[pp][c8 + 4] = fk2;
      *(float4*)&Vs[pp][c8] = fv1; *(float4*)&Vs[pp][c8 + 4] = fv2;
    }
    __syncthreads();
#pragma unroll 4
    for (int pp = 0; pp < 64; ++pp) {
      float4 kk = *(const float4*)&Ks[pp][ty * 4];
      float4 vv = *(const float4*)&Vs[pp][tx * 4];
      const float* kkp = (const float*)&kk;
      const float* vvp = (const float*)&vv;
#pragma unroll
      for (int i = 0; i < 4; ++i)
#pragma unroll
        for (int j = 0; j < 4; ++j) acc[i][j] += kkp[i] * vvp[j];
    }
  }
  float* kt = ktv + bh * 4096;
#pragma unroll
  for (int i = 0; i < 4; ++i)
#pragma unroll
    for (int j = 0; j < 4; ++j)
      atomicAdd(&kt[(ty * 4 + i) * 64 + tx * 4 + j], acc[i][j]);
}

// ---------- out[bn][e] = (m0 - diag)*v + SCALE * sum_d q[bn][d]*ktv[d][e] ----------
__global__ __launch_bounds__(256) void attn_out_kernel(
    const u16* __restrict__ Q, const u16* __restrict__ KV,
    const float* __restrict__ dg, const float* __restrict__ ktv,
    const float* __restrict__ m0p, u16* __restrict__ OutA)
{
  int bh = blockIdx.y, bb = bh >> 3, hh = bh & 7;
  int p0 = blockIdx.x * 64;
  __shared__ float Qs[64][68];   // [d][pp]  (transposed at stage)
  __shared__ float Kt[64][68];   // [d][e]
  __shared__ float Vs[64][68];   // [pp][e]
  __shared__ float ds_[64];
  int tid = threadIdx.x;
  const float* kt = ktv + bh * 4096;
  for (int l = tid; l < 4096; l += 256) Kt[l >> 6][l & 63] = kt[l];
  for (int l = tid; l < 512; l += 256) {
    int pp = l >> 3, c8 = (l & 7) * 8;
    const u16* qrow = Q + ((size_t)bb * N_SP + p0 + pp) * NINNER + hh * 64 + c8;
    ushort4 q1 = *(const ushort4*)qrow, q2 = *(const ushort4*)(qrow + 4);
    Qs[c8 + 0][pp] = bf2f(q1.x); Qs[c8 + 1][pp] = bf2f(q1.y);
    Qs[c8 + 2][pp] = bf2f(q1.z); Qs[c8 + 3][pp] = bf2f(q1.w);
    Qs[c8 + 4][pp] = bf2f(q2.x); Qs[c8 + 5][pp] = bf2f(q2.y);
    Qs[c8 + 6][pp] = bf2f(q2.z); Qs[c8 + 7][pp] = bf2f(q2.w);
    const u16* vrow = KV + ((size_t)bb * N_SP + p0 + pp) * (2 * NINNER) + NINNER + hh * 64 + c8;
    ushort4 v1 = *(const ushort4*)vrow, v2 = *(const ushort4*)(vrow + 4);
    float4 fv1 = {bf2f(v1.x), bf2f(v1.y), bf2f(v1.z), bf2f(v1.w)};
    float4 fv2 = {bf2f(v2.x), bf2f(v2.y), bf2f(v2.z), bf2f(v2.w)};
    *(float4*)&Vs[pp][c8] = fv1; *(float4*)&Vs[pp][c8 + 4] = fv2;
  }
  if (tid < 64) ds_[tid] = dg[((size_t)bb * N_SP + p0 + tid) * 8 + hh];
  __syncthreads();
  float m0v = *m0p;
  int tx = tid & 15, ty = tid >> 4;
  int e0 = tx * 4, pq = ty * 4;
  float acc[4][4] = {{0.f}};   // [pi][ej]
#pragma unroll 8
  for (int d = 0; d < 64; ++d) {
    float4 qv = *(const float4*)&Qs[d][pq];
    float4 kv4 = *(const float4*)&Kt[d][e0];
    const float* q_ = (const float*)&qv;
#pragma unroll
    for (int pi = 0; pi < 4; ++pi) {
      acc[pi][0] += q_[pi] * kv4.x;
      acc[pi][1] += q_[pi] * kv4.y;
      acc[pi][2] += q_[pi] * kv4.z;
      acc[pi][3] += q_[pi] * kv4.w;
    }
  }
#pragma unroll
  for (int pi = 0; pi < 4; ++pi) {
    float dv = m0v - ds_[pq + pi];
    ushort4 ov;
    ov.x = f2bf(SCALE_F * acc[pi][0] + dv * Vs[pq + pi][e0 + 0]);
    ov.y = f2bf(SCALE_F * acc[pi][1] + dv * Vs[pq + pi][e0 + 1]);
    ov.z = f2bf(SCALE_F * acc[pi][2] + dv * Vs[pq + pi][e0 + 2]);
    ov.w = f2bf(SCALE_F * acc[pi][3] + dv * Vs[pq + pi][e0 + 3]);
    *(ushort4*)(OutA + ((size_t)bb * N_SP + p0 + pq + pi) * NINNER + hh * 64 + e0) = ov;
  }
}

extern "C" void kernel_launch(void* const* d_in, const int* in_sizes, int n_in,
                              void* d_out, int out_size, void* d_ws, size_t ws_size,
                              hipStream_t stream)
{
  (void)in_sizes; (void)n_in; (void)out_size; (void)ws_size;
  const float* x      = (const float*)d_in[0];
  const float* wq_dw  = (const float*)d_in[1];
  const float* wq_g   = (const float*)d_in[2];
  const float* wq_b   = (const float*)d_in[3];
  const float* wq_m   = (const float*)d_in[4];
  const float* wq_v   = (const float*)d_in[5];
  const float* wq_pw  = (const float*)d_in[6];
  const float* wkv_dw = (const float*)d_in[7];
  const float* wkv_g  = (const float*)d_in[8];
  const float* wkv_b  = (const float*)d_in[9];
  const float* wkv_m  = (const float*)d_in[10];
  const float* wkv_v  = (const float*)d_in[11];
  const float* wkv_pw = (const float*)d_in[12];
  const float* wo     = (const float*)d_in[13];
  const float* bo     = (const float*)d_in[14];
  float* out = (float*)d_out;

  char* ws = (char*)d_ws;
  size_t off = 0;
  auto alloc = [&](size_t bytes) {
    void* p = ws + off; off = (off + bytes + 255) & ~(size_t)255; return p;
  };
  u16* yq   = (u16*)alloc((size_t)BNCOL * NDIM * 2);        // 19.27 MB  (BN, 384)
  u16* ykv  = (u16*)alloc((size_t)BNCOL * NDIM * 2);        // 19.27 MB
  u16* Qb   = (u16*)alloc((size_t)BNCOL * NINNER * 2);      // 25.69 MB  (BN, 512)
  u16* KVb  = (u16*)alloc((size_t)BNCOL * 2 * NINNER * 2);  // 51.38 MB  (BN, 1024)
  float* dgb  = (float*)alloc((size_t)BNCOL * 8 * 4);       // 0.80 MB   (bn, h)
  float* ktvb = (float*)alloc((size_t)64 * 4096 * 4 + 64);  // 1.05 MB (+m0 tail)
  u16* Wq  = (u16*)alloc((size_t)NINNER * NDIM * 2);        // 0.39 MB
  u16* Wkv = (u16*)alloc((size_t)2 * NINNER * NDIM * 2);    // 0.79 MB
  u16* Wo  = (u16*)alloc((size_t)NDIM * NINNER * 2);        // 0.39 MB
  float* m0 = ktvb + 64 * 4096;
  u16* OutA = yq;   // alias: yq/ykv dead after the pw GEMMs; 25.7 MB fits in their 38.5 MB

  hipMemsetAsync(ktvb, 0, (size_t)64 * 4096 * 4 + 4, stream);

  cvt_kernel<<<1536, 256, 0, stream>>>(wq_pw, wkv_pw, wo, Wq, Wkv, Wo);

  dwbn_kernel<<<dim3(49, 12, 8), 256, 0, stream>>>(
      x, wq_dw, wq_g, wq_b, wq_m, wq_v,
      wkv_dw, wkv_g, wkv_b, wkv_m, wkv_v, yq, ykv);

  mfma_gemm<<<dim3(196, 4), 256, 0, stream>>>(Wq, yq, NDIM, Qb, NINNER, 0, nullptr, nullptr);
  mfma_gemm<<<dim3(196, 8), 256, 0, stream>>>(Wkv, ykv, NDIM, KVb, 2 * NINNER, 0, nullptr, nullptr);

  diag_kernel<<<784, 256, 0, stream>>>(Qb, KVb, dgb, m0);
  ktv_kernel<<<dim3(7, 64), 256, 0, stream>>>(KVb, ktvb);
  attn_out_kernel<<<dim3(49, 64), 256, 0, stream>>>(Qb, KVb, dgb, ktvb, m0, OutA);

  mfma_gemm<<<dim3(196, 3), 256, 0, stream>>>(Wo, OutA, NINNER, nullptr, 0, 1, bo, out);
}

// Round 4
// 341.747 us; speedup vs baseline: 2.5815x; 1.2466x over previous
//
#include <hip/hip_runtime.h>

typedef unsigned short u16;

#define N_SP   3136     // 56*56
#define BNCOL  25088    // B * N_SP
#define NDIM   384
#define NINNER 512
#define SCALE_F 0.125f

typedef __attribute__((ext_vector_type(8))) short bf16x8;
typedef __attribute__((ext_vector_type(4))) float f32x4;

#define AS1 __attribute__((address_space(1)))
#define AS3 __attribute__((address_space(3)))

__device__ __forceinline__ float bf2f(u16 u) {
  union { unsigned int i; float f; } v; v.i = ((unsigned int)u) << 16; return v.f;
}
__device__ __forceinline__ u16 f2bf(float f) {
  union { float f; unsigned int i; } v; v.f = f;
  unsigned int r = v.i + 0x7fffu + ((v.i >> 16) & 1u);   // RNE
  return (u16)(r >> 16);
}

// async global->LDS, 16B per lane. lds base must be wave-uniform; lane i lands at lds + i*16B.
__device__ __forceinline__ void g2l16(const u16* g, u16* l) {
  __builtin_amdgcn_global_load_lds((const AS1 unsigned int*)g,
                                   (AS3 unsigned int*)l, 16, 0, 0);
}

// ---------- weight fp32 -> bf16 convert + BN-folded depthwise weights ----------
__global__ __launch_bounds__(256) void cvt_kernel(
    const float* __restrict__ a, const float* __restrict__ b, const float* __restrict__ c,
    u16* __restrict__ oa, u16* __restrict__ ob, u16* __restrict__ oc,
    const float* __restrict__ qdw, const float* __restrict__ qg, const float* __restrict__ qb2,
    const float* __restrict__ qm,  const float* __restrict__ qv,
    const float* __restrict__ kdw, const float* __restrict__ kg, const float* __restrict__ kb2,
    const float* __restrict__ km,  const float* __restrict__ kvv,
    float* __restrict__ fused)
{
  int i = blockIdx.x * 256 + threadIdx.x;
  if (i < 196608) oa[i] = f2bf(a[i]);
  ob[i] = f2bf(b[i]);               // grid sized exactly to 393216
  if (i < 196608) oc[i] = f2bf(c[i]);
  if (i < NDIM) {
    float invq = qg[i] * rsqrtf(qv[i] + 1e-5f);
    float invk = kg[i] * rsqrtf(kvv[i] + 1e-5f);
    float* f = fused + i * 20;
#pragma unroll
    for (int j = 0; j < 9; ++j) { f[j] = qdw[i*9+j] * invq; f[10+j] = kdw[i*9+j] * invk; }
    f[9]  = qb2[i] - qm[i] * invq;
    f[19] = kb2[i] - km[i] * invk;
  }
}

// ---------- fused depthwise 3x3 conv + BN (q and kv paths), output (BN, C) bf16 ----------
// branch-free: clamped safe addresses + float masks -> 72 independent loads (deep MLP)
__global__ __launch_bounds__(256) void dwbn_kernel(
    const float* __restrict__ x, const float* __restrict__ fused,
    u16* __restrict__ yq, u16* __restrict__ ykv)
{
  __shared__ u16 Lq[64][40];
  __shared__ u16 Lk[64][40];
  int tid = threadIdx.x;
  int bb = blockIdx.z, c0 = blockIdx.y * 32, p0 = blockIdx.x * 64;
  int pl = tid & 63;
  int cg = __builtin_amdgcn_readfirstlane(tid >> 6);   // wave-uniform channel group
  int p = p0 + pl;
  int h = p / 56, w = p - h * 56;
  int roff[3], coff[3];
  float mr[3], mc[3];
#pragma unroll
  for (int d = 0; d < 3; ++d) {
    int r = h + d - 1;
    bool vr = (r >= 0) && (r < 56);
    roff[d] = (vr ? r : h) * 56;
    mr[d] = vr ? 1.f : 0.f;
    int cc = w + d - 1;
    bool vc = (cc >= 0) && (cc < 56);
    coff[d] = vc ? cc : w;
    mc[d] = vc ? 1.f : 0.f;
  }
  float m9[9];
#pragma unroll
  for (int dh = 0; dh < 3; ++dh)
#pragma unroll
    for (int dw = 0; dw < 3; ++dw) m9[dh*3+dw] = mr[dh] * mc[dw];

  __attribute__((aligned(16))) u16 oq[8], ok[8];
#pragma unroll
  for (int i = 0; i < 8; ++i) {
    int c = c0 + cg * 8 + i;
    const float* xp = x + ((size_t)bb * NDIM + c) * N_SP;
    const float* f = fused + c * 20;
    float v[9];
#pragma unroll
    for (int dh = 0; dh < 3; ++dh)
#pragma unroll
      for (int dw = 0; dw < 3; ++dw)
        v[dh*3+dw] = xp[roff[dh] + coff[dw]];
    float sq = f[9], sk = f[19];
#pragma unroll
    for (int j = 0; j < 9; ++j) {
      float xm = v[j] * m9[j];
      sq += xm * f[j];
      sk += xm * f[10+j];
    }
    oq[i] = f2bf(sq); ok[i] = f2bf(sk);
  }
  *(ushort4*)&Lq[pl][cg * 8]     = *(ushort4*)&oq[0];
  *(ushort4*)&Lq[pl][cg * 8 + 4] = *(ushort4*)&oq[4];
  *(ushort4*)&Lk[pl][cg * 8]     = *(ushort4*)&ok[0];
  *(ushort4*)&Lk[pl][cg * 8 + 4] = *(ushort4*)&ok[4];
  __syncthreads();
  int pr = tid >> 2, cc2 = (tid & 3) * 8;
  size_t g = ((size_t)bb * N_SP + p0 + pr) * NDIM + c0 + cc2;
  *(ushort4*)(yq + g)      = *(ushort4*)&Lq[pr][cc2];
  *(ushort4*)(yq + g + 4)  = *(ushort4*)&Lq[pr][cc2 + 4];
  *(ushort4*)(ykv + g)     = *(ushort4*)&Lk[pr][cc2];
  *(ushort4*)(ykv + g + 4) = *(ushort4*)&Lk[pr][cc2 + 4];
}

// ---------- MFMA GEMM: D[m][n] = sum_k W[m][k] * Act[n][k]  (NT form) ----------
// W: bf16 M x Kd row-major. Act: bf16 BN x Kd row-major (row stride == Kd).
// mode 0: transpose-store bf16 to Cout (BN x Cstride) at column m.
// mode 1: +bias, scatter fp32 to (B, 384, 3136) NCHW output.
__global__ __launch_bounds__(256) void mfma_gemm(
    const u16* __restrict__ W, const u16* __restrict__ Act, int Kd,
    u16* __restrict__ Cout, int Cstride,
    int mode, const float* __restrict__ bias, float* __restrict__ Out)
{
  __shared__ union {
    struct { u16 A[128 * 32]; u16 B[128 * 32]; } s;   // [row][k] 8KB each
    u16 T[128 * 132];                                  // epilogue transpose [n][m]
  } lds;
  int tid = threadIdx.x;
  int lane = tid & 63, wv = tid >> 6;
  int wm = (wv >> 1) * 64, wn = (wv & 1) * 64;
  int m0 = blockIdx.y * 128, n0 = blockIdx.x * 128;
  int srow = lane >> 2;          // 0..15
  int sch = (lane & 3) * 8;      // k chunk
  int arow0 = wv * 32;           // each wave stages 32 rows of A and B
  const u16* Wg   = W   + (size_t)(m0 + arow0 + srow) * Kd + sch;
  const u16* Actg = Act + (size_t)(n0 + arow0 + srow) * Kd + sch;
  u16* Al = &lds.s.A[arow0 * 32];
  u16* Bl = &lds.s.B[arow0 * 32];
  f32x4 acc[4][4];
#pragma unroll
  for (int i = 0; i < 4; ++i)
#pragma unroll
    for (int j = 0; j < 4; ++j) acc[i][j] = (f32x4){0.f, 0.f, 0.f, 0.f};

  int ml = lane & 15, q8 = (lane >> 4) * 8;
  for (int k0 = 0; k0 < Kd; k0 += 32) {
    g2l16(Wg + k0, Al);
    g2l16(Wg + k0 + (size_t)16 * Kd, Al + 16 * 32);
    g2l16(Actg + k0, Bl);
    g2l16(Actg + k0 + (size_t)16 * Kd, Bl + 16 * 32);
    __syncthreads();
    bf16x8 af[4], bfr[4];
#pragma unroll
    for (int i = 0; i < 4; ++i) {
      af[i]  = *(const bf16x8*)&lds.s.A[(wm + i * 16 + ml) * 32 + q8];
      bfr[i] = *(const bf16x8*)&lds.s.B[(wn + i * 16 + ml) * 32 + q8];
    }
#pragma unroll
    for (int i = 0; i < 4; ++i)
#pragma unroll
      for (int j = 0; j < 4; ++j)
        acc[i][j] = __builtin_amdgcn_mfma_f32_16x16x32_bf16(af[i], bfr[j], acc[i][j], 0, 0, 0);
    __syncthreads();
  }

  if (mode == 0) {
    int q4 = (lane >> 4) * 4;
#pragma unroll
    for (int i = 0; i < 4; ++i)
#pragma unroll
      for (int j = 0; j < 4; ++j) {
        int n = wn + j * 16 + ml;
        int m = wm + i * 16 + q4;
        ushort4 o;
        o.x = f2bf(acc[i][j][0]); o.y = f2bf(acc[i][j][1]);
        o.z = f2bf(acc[i][j][2]); o.w = f2bf(acc[i][j][3]);
        *(ushort4*)&lds.T[n * 132 + m] = o;   // T[n][m..m+3]
      }
    __syncthreads();
#pragma unroll
    for (int it = 0; it < 8; ++it) {
      int n = it * 16 + (tid >> 4);
      int mc = (tid & 15) * 8;
      ushort4 a = *(ushort4*)&lds.T[n * 132 + mc];
      ushort4 b = *(ushort4*)&lds.T[n * 132 + mc + 4];
      u16* gp = Cout + (size_t)(n0 + n) * Cstride + m0 + mc;
      *(ushort4*)gp = a;
      *(ushort4*)(gp + 4) = b;
    }
  } else {
    int q4 = (lane >> 4) * 4;
#pragma unroll
    for (int i = 0; i < 4; ++i)
#pragma unroll
      for (int j = 0; j < 4; ++j) {
        int n = n0 + wn + j * 16 + ml;
        int bb = n / N_SP, p = n - bb * N_SP;
#pragma unroll
        for (int r = 0; r < 4; ++r) {
          int m = m0 + wm + i * 16 + q4 + r;
          Out[((size_t)bb * NDIM + m) * N_SP + p] = acc[i][j][r] + bias[m];
        }
      }
  }
}

// ---------- diag[bn][h] = SCALE * sum_d q.k ; m0 = sum ----------
__global__ __launch_bounds__(256) void diag_kernel(
    const u16* __restrict__ Q, const u16* __restrict__ KV,
    float* __restrict__ dg, float* __restrict__ m0)
{
  int t = blockIdx.x * 256 + threadIdx.x;
  int bn = t >> 3, hh = t & 7;
  const u16* qp = Q + (size_t)bn * NINNER + hh * 64;
  const u16* kp = KV + (size_t)bn * (2 * NINNER) + hh * 64;
  float s = 0.f;
#pragma unroll
  for (int j = 0; j < 16; ++j) {
    ushort4 a = *(const ushort4*)(qp + 4 * j);
    ushort4 b = *(const ushort4*)(kp + 4 * j);
    s += bf2f(a.x) * bf2f(b.x) + bf2f(a.y) * bf2f(b.y)
       + bf2f(a.z) * bf2f(b.z) + bf2f(a.w) * bf2f(b.w);
  }
  s *= SCALE_F;
  dg[t] = s;
  float r = s;
#pragma unroll
  for (int off = 32; off > 0; off >>= 1) r += __shfl_down(r, off);
  __shared__ float wsum[4];
  if ((threadIdx.x & 63) == 0) wsum[threadIdx.x >> 6] = r;
  __syncthreads();
  if (threadIdx.x == 0) atomicAdd(m0, wsum[0] + wsum[1] + wsum[2] + wsum[3]);
}

// ---------- ktv[bh][d][e] = sum_p k[p][d] v[p][e]  (p-split x7, fp32 atomics) ----------
__global__ __launch_bounds__(256) void ktv_kernel(
    const u16* __restrict__ KV, float* __restrict__ ktv)
{
  int bh = blockIdx.y, bb = bh >> 3, hh = bh & 7;
  __shared__ float Ks[64][68];   // [pp][d]
  __shared__ float Vs[64][68];   // [pp][e]
  int tid = threadIdx.x, tx = tid & 15, ty = tid >> 4;
  float acc[4][4] = {{0.f}};
  for (int ch = 0; ch < 7; ++ch) {
    int p0 = blockIdx.x * 448 + ch * 64;
    __syncthreads();
    for (int l = tid; l < 512; l += 256) {
      int pp = l >> 3, c8 = (l & 7) * 8;
      const u16* row = KV + ((size_t)bb * N_SP + p0 + pp) * (2 * NINNER) + hh * 64 + c8;
      ushort4 k1 = *(const ushort4*)row, k2 = *(const ushort4*)(row + 4);
      ushort4 v1 = *(const ushort4*)(row + NINNER), v2 = *(const ushort4*)(row + NINNER + 4);
      float4 fk1 = {bf2f(k1.x), bf2f(k1.y), bf2f(k1.z), bf2f(k1.w)};
      float4 fk2 = {bf2f(k2.x), bf2f(k2.y), bf2f(k2.z), bf2f(k2.w)};
      float4 fv1 = {bf2f(v1.x), bf2f(v1.y), bf2f(v1.z), bf2f(v1.w)};
      float4 fv2 = {bf2f(v2.x), bf2f(v2.y), bf2f(v2.z), bf2f(v2.w)};
      *(float4*)&Ks[pp][c8] = fk1; *(float4*)&Ks[pp][c8 + 4] = fk2;
      *(float4*)&Vs[pp][c8] = fv1; *(float4*)&Vs[pp][c8 + 4] = fv2;
    }
    __syncthreads();
#pragma unroll 4
    for (int pp = 0; pp < 64; ++pp) {
      float4 kk = *(const float4*)&Ks[pp][ty * 4];
      float4 vv = *(const float4*)&Vs[pp][tx * 4];
      const float* kkp = (const float*)&kk;
      const float* vvp = (const float*)&vv;
#pragma unroll
      for (int i = 0; i < 4; ++i)
#pragma unroll
        for (int j = 0; j < 4; ++j) acc[i][j] += kkp[i] * vvp[j];
    }
  }
  float* kt = ktv + bh * 4096;
#pragma unroll
  for (int i = 0; i < 4; ++i)
#pragma unroll
    for (int j = 0; j < 4; ++j)
      atomicAdd(&kt[(ty * 4 + i) * 64 + tx * 4 + j], acc[i][j]);
}

// ---------- out[bn][e] = (m0 - diag)*v + SCALE * sum_d q[bn][d]*ktv[d][e] ----------
__global__ __launch_bounds__(256) void attn_out_kernel(
    const u16* __restrict__ Q, const u16* __restrict__ KV,
    const float* __restrict__ dg, const float* __restrict__ ktv,
    const float* __restrict__ m0p, u16* __restrict__ OutA)
{
  int bh = blockIdx.y, bb = bh >> 3, hh = bh & 7;
  int p0 = blockIdx.x * 64;
  __shared__ float Qs[64][68];   // [d][pp]  (transposed at stage)
  __shared__ float Kt[64][68];   // [d][e]
  __shared__ float Vs[64][68];   // [pp][e]
  __shared__ float ds_[64];
  int tid = threadIdx.x;
  const float* kt = ktv + bh * 4096;
  for (int l = tid; l < 4096; l += 256) Kt[l >> 6][l & 63] = kt[l];
  for (int l = tid; l < 512; l += 256) {
    int pp = l >> 3, c8 = (l & 7) * 8;
    const u16* qrow = Q + ((size_t)bb * N_SP + p0 + pp) * NINNER + hh * 64 + c8;
    ushort4 q1 = *(const ushort4*)qrow, q2 = *(const ushort4*)(qrow + 4);
    Qs[c8 + 0][pp] = bf2f(q1.x); Qs[c8 + 1][pp] = bf2f(q1.y);
    Qs[c8 + 2][pp] = bf2f(q1.z); Qs[c8 + 3][pp] = bf2f(q1.w);
    Qs[c8 + 4][pp] = bf2f(q2.x); Qs[c8 + 5][pp] = bf2f(q2.y);
    Qs[c8 + 6][pp] = bf2f(q2.z); Qs[c8 + 7][pp] = bf2f(q2.w);
    const u16* vrow = KV + ((size_t)bb * N_SP + p0 + pp) * (2 * NINNER) + NINNER + hh * 64 + c8;
    ushort4 v1 = *(const ushort4*)vrow, v2 = *(const ushort4*)(vrow + 4);
    float4 fv1 = {bf2f(v1.x), bf2f(v1.y), bf2f(v1.z), bf2f(v1.w)};
    float4 fv2 = {bf2f(v2.x), bf2f(v2.y), bf2f(v2.z), bf2f(v2.w)};
    *(float4*)&Vs[pp][c8] = fv1; *(float4*)&Vs[pp][c8 + 4] = fv2;
  }
  if (tid < 64) ds_[tid] = dg[((size_t)bb * N_SP + p0 + tid) * 8 + hh];
  __syncthreads();
  float m0v = *m0p;
  int tx = tid & 15, ty = tid >> 4;
  int e0 = tx * 4, pq = ty * 4;
  float acc[4][4] = {{0.f}};   // [pi][ej]
#pragma unroll 8
  for (int d = 0; d < 64; ++d) {
    float4 qv = *(const float4*)&Qs[d][pq];
    float4 kv4 = *(const float4*)&Kt[d][e0];
    const float* q_ = (const float*)&qv;
#pragma unroll
    for (int pi = 0; pi < 4; ++pi) {
      acc[pi][0] += q_[pi] * kv4.x;
      acc[pi][1] += q_[pi] * kv4.y;
      acc[pi][2] += q_[pi] * kv4.z;
      acc[pi][3] += q_[pi] * kv4.w;
    }
  }
#pragma unroll
  for (int pi = 0; pi < 4; ++pi) {
    float dv = m0v - ds_[pq + pi];
    ushort4 ov;
    ov.x = f2bf(SCALE_F * acc[pi][0] + dv * Vs[pq + pi][e0 + 0]);
    ov.y = f2bf(SCALE_F * acc[pi][1] + dv * Vs[pq + pi][e0 + 1]);
    ov.z = f2bf(SCALE_F * acc[pi][2] + dv * Vs[pq + pi][e0 + 2]);
    ov.w = f2bf(SCALE_F * acc[pi][3] + dv * Vs[pq + pi][e0 + 3]);
    *(ushort4*)(OutA + ((size_t)bb * N_SP + p0 + pq + pi) * NINNER + hh * 64 + e0) = ov;
  }
}

extern "C" void kernel_launch(void* const* d_in, const int* in_sizes, int n_in,
                              void* d_out, int out_size, void* d_ws, size_t ws_size,
                              hipStream_t stream)
{
  (void)in_sizes; (void)n_in; (void)out_size; (void)ws_size;
  const float* x      = (const float*)d_in[0];
  const float* wq_dw  = (const float*)d_in[1];
  const float* wq_g   = (const float*)d_in[2];
  const float* wq_b   = (const float*)d_in[3];
  const float* wq_m   = (const float*)d_in[4];
  const float* wq_v   = (const float*)d_in[5];
  const float* wq_pw  = (const float*)d_in[6];
  const float* wkv_dw = (const float*)d_in[7];
  const float* wkv_g  = (const float*)d_in[8];
  const float* wkv_b  = (const float*)d_in[9];
  const float* wkv_m  = (const float*)d_in[10];
  const float* wkv_v  = (const float*)d_in[11];
  const float* wkv_pw = (const float*)d_in[12];
  const float* wo     = (const float*)d_in[13];
  const float* bo     = (const float*)d_in[14];
  float* out = (float*)d_out;

  char* ws = (char*)d_ws;
  size_t off = 0;
  auto alloc = [&](size_t bytes) {
    void* p = ws + off; off = (off + bytes + 255) & ~(size_t)255; return p;
  };
  u16* yq   = (u16*)alloc((size_t)BNCOL * NDIM * 2);        // 19.27 MB  (BN, 384)
  u16* ykv  = (u16*)alloc((size_t)BNCOL * NDIM * 2);        // 19.27 MB
  u16* Qb   = (u16*)alloc((size_t)BNCOL * NINNER * 2);      // 25.69 MB  (BN, 512)
  u16* KVb  = (u16*)alloc((size_t)BNCOL * 2 * NINNER * 2);  // 51.38 MB  (BN, 1024)
  float* dgb  = (float*)alloc((size_t)BNCOL * 8 * 4);       // 0.80 MB   (bn, h)
  float* ktvb = (float*)alloc((size_t)64 * 4096 * 4 + 64);  // 1.05 MB (+m0 tail)
  u16* Wq  = (u16*)alloc((size_t)NINNER * NDIM * 2);        // 0.39 MB
  u16* Wkv = (u16*)alloc((size_t)2 * NINNER * NDIM * 2);    // 0.79 MB
  u16* Wo  = (u16*)alloc((size_t)NDIM * NINNER * 2);        // 0.39 MB
  float* fused = (float*)alloc((size_t)NDIM * 20 * 4);      // 30.7 KB BN-folded dw weights
  float* m0 = ktvb + 64 * 4096;
  u16* OutA = yq;   // alias: yq/ykv dead after the pw GEMMs; 25.7 MB fits in their 38.5 MB

  hipMemsetAsync(ktvb, 0, (size_t)64 * 4096 * 4 + 4, stream);

  cvt_kernel<<<1536, 256, 0, stream>>>(wq_pw, wkv_pw, wo, Wq, Wkv, Wo,
                                       wq_dw, wq_g, wq_b, wq_m, wq_v,
                                       wkv_dw, wkv_g, wkv_b, wkv_m, wkv_v, fused);

  dwbn_kernel<<<dim3(49, 12, 8), 256, 0, stream>>>(x, fused, yq, ykv);

  mfma_gemm<<<dim3(196, 4), 256, 0, stream>>>(Wq, yq, NDIM, Qb, NINNER, 0, nullptr, nullptr);
  mfma_gemm<<<dim3(196, 8), 256, 0, stream>>>(Wkv, ykv, NDIM, KVb, 2 * NINNER, 0, nullptr, nullptr);

  diag_kernel<<<784, 256, 0, stream>>>(Qb, KVb, dgb, m0);
  ktv_kernel<<<dim3(7, 64), 256, 0, stream>>>(KVb, ktvb);
  attn_out_kernel<<<dim3(49, 64), 256, 0, stream>>>(Qb, KVb, dgb, ktvb, m0, OutA);

  mfma_gemm<<<dim3(196, 3), 256, 0, stream>>>(Wo, OutA, NINNER, nullptr, 0, 1, bo, out);
}

// Round 5
// 308.411 us; speedup vs baseline: 2.8605x; 1.1081x over previous
//
#include <hip/hip_runtime.h>

typedef unsigned short u16;

#define N_SP   3136     // 56*56
#define BNCOL  25088    // B * N_SP
#define NDIM   384
#define NINNER 512
#define SCALE_F 0.125f

typedef __attribute__((ext_vector_type(8))) short bf16x8;
typedef __attribute__((ext_vector_type(4))) float f32x4;

#define AS1 __attribute__((address_space(1)))
#define AS3 __attribute__((address_space(3)))

__device__ __forceinline__ float bf2f(u16 u) {
  union { unsigned int i; float f; } v; v.i = ((unsigned int)u) << 16; return v.f;
}
__device__ __forceinline__ u16 f2bf(float f) {
  union { float f; unsigned int i; } v; v.f = f;
  unsigned int r = v.i + 0x7fffu + ((v.i >> 16) & 1u);   // RNE
  return (u16)(r >> 16);
}

// async global->LDS, 16B per lane. lds base must be wave-uniform; lane i lands at lds + i*16B.
__device__ __forceinline__ void g2l16(const u16* g, u16* l) {
  __builtin_amdgcn_global_load_lds((const AS1 unsigned int*)g,
                                   (AS3 unsigned int*)l, 16, 0, 0);
}

// ---------- weight fp32 -> bf16 convert + BN-folded depthwise weights ----------
__global__ __launch_bounds__(256) void cvt_kernel(
    const float* __restrict__ a, const float* __restrict__ b, const float* __restrict__ c,
    u16* __restrict__ oa, u16* __restrict__ ob, u16* __restrict__ oc,
    const float* __restrict__ qdw, const float* __restrict__ qg, const float* __restrict__ qb2,
    const float* __restrict__ qm,  const float* __restrict__ qv,
    const float* __restrict__ kdw, const float* __restrict__ kg, const float* __restrict__ kb2,
    const float* __restrict__ km,  const float* __restrict__ kvv,
    float* __restrict__ fused)
{
  int i = blockIdx.x * 256 + threadIdx.x;
  if (i < 196608) oa[i] = f2bf(a[i]);
  ob[i] = f2bf(b[i]);               // grid sized exactly to 393216
  if (i < 196608) oc[i] = f2bf(c[i]);
  if (i < NDIM) {
    float invq = qg[i] * rsqrtf(qv[i] + 1e-5f);
    float invk = kg[i] * rsqrtf(kvv[i] + 1e-5f);
    float* f = fused + i * 20;
#pragma unroll
    for (int j = 0; j < 9; ++j) { f[j] = qdw[i*9+j] * invq; f[10+j] = kdw[i*9+j] * invk; }
    f[9]  = qb2[i] - qm[i] * invq;
    f[19] = kb2[i] - km[i] * invk;
  }
}

// ---------- fused depthwise 3x3 conv + BN (q and kv paths), output (BN, C) bf16 ----------
// branch-free: clamped safe addresses + float masks -> 72 independent loads (deep MLP)
__global__ __launch_bounds__(256) void dwbn_kernel(
    const float* __restrict__ x, const float* __restrict__ fused,
    u16* __restrict__ yq, u16* __restrict__ ykv)
{
  __shared__ u16 Lq[64][40];
  __shared__ u16 Lk[64][40];
  int tid = threadIdx.x;
  int bb = blockIdx.z, c0 = blockIdx.y * 32, p0 = blockIdx.x * 64;
  int pl = tid & 63;
  int cg = __builtin_amdgcn_readfirstlane(tid >> 6);   // wave-uniform channel group
  int p = p0 + pl;
  int h = p / 56, w = p - h * 56;
  int roff[3], coff[3];
  float mr[3], mc[3];
#pragma unroll
  for (int d = 0; d < 3; ++d) {
    int r = h + d - 1;
    bool vr = (r >= 0) && (r < 56);
    roff[d] = (vr ? r : h) * 56;
    mr[d] = vr ? 1.f : 0.f;
    int cc = w + d - 1;
    bool vc = (cc >= 0) && (cc < 56);
    coff[d] = vc ? cc : w;
    mc[d] = vc ? 1.f : 0.f;
  }
  float m9[9];
#pragma unroll
  for (int dh = 0; dh < 3; ++dh)
#pragma unroll
    for (int dw = 0; dw < 3; ++dw) m9[dh*3+dw] = mr[dh] * mc[dw];

  __attribute__((aligned(16))) u16 oq[8], ok[8];
#pragma unroll
  for (int i = 0; i < 8; ++i) {
    int c = c0 + cg * 8 + i;
    const float* xp = x + ((size_t)bb * NDIM + c) * N_SP;
    const float* f = fused + c * 20;
    float v[9];
#pragma unroll
    for (int dh = 0; dh < 3; ++dh)
#pragma unroll
      for (int dw = 0; dw < 3; ++dw)
        v[dh*3+dw] = xp[roff[dh] + coff[dw]];
    float sq = f[9], sk = f[19];
#pragma unroll
    for (int j = 0; j < 9; ++j) {
      float xm = v[j] * m9[j];
      sq += xm * f[j];
      sk += xm * f[10+j];
    }
    oq[i] = f2bf(sq); ok[i] = f2bf(sk);
  }
  *(ushort4*)&Lq[pl][cg * 8]     = *(ushort4*)&oq[0];
  *(ushort4*)&Lq[pl][cg * 8 + 4] = *(ushort4*)&oq[4];
  *(ushort4*)&Lk[pl][cg * 8]     = *(ushort4*)&ok[0];
  *(ushort4*)&Lk[pl][cg * 8 + 4] = *(ushort4*)&ok[4];
  __syncthreads();
  int pr = tid >> 2, cc2 = (tid & 3) * 8;
  size_t g = ((size_t)bb * N_SP + p0 + pr) * NDIM + c0 + cc2;
  *(ushort4*)(yq + g)      = *(ushort4*)&Lq[pr][cc2];
  *(ushort4*)(yq + g + 4)  = *(ushort4*)&Lq[pr][cc2 + 4];
  *(ushort4*)(ykv + g)     = *(ushort4*)&Lk[pr][cc2];
  *(ushort4*)(ykv + g + 4) = *(ushort4*)&Lk[pr][cc2 + 4];
}

// ---------- MFMA GEMM: D[m][n] = sum_k W[m][k] * Act[n][k]  (NT form) ----------
// 1-D grid, XCD-pinned swizzle: bid&7 -> XCD slot keeps one n-tile while m sweeps.
// mode 0: transpose-store bf16 to Cout (BN x Cstride). mode 1: +bias, fp32 NCHW scatter.
__global__ __launch_bounds__(256) void mfma_gemm(
    const u16* __restrict__ W, const u16* __restrict__ Act, int Kd,
    u16* __restrict__ Cout, int Cstride,
    int mode, const float* __restrict__ bias, float* __restrict__ Out, int Mt)
{
  __shared__ union {
    struct { u16 A[128 * 32]; u16 B[128 * 32]; } s;   // [row][k] 8KB each
    u16 T[64 * 132];                                   // epilogue transpose chunk (16.9KB)
  } lds;
  int bid = blockIdx.x;
  int r = bid & 7, g = bid >> 3;
  int mt = g % Mt, nt = (g / Mt) * 8 + r;
  if (nt >= 196) return;
  int m0 = mt * 128, n0 = nt * 128;

  int tid = threadIdx.x;
  int lane = tid & 63, wv = tid >> 6;
  int wm = (wv >> 1) * 64, wn = (wv & 1) * 64;
  int srow = lane >> 2;          // 0..15
  int sch = (lane & 3) * 8;      // k chunk
  int arow0 = wv * 32;           // each wave stages 32 rows of A and B
  const u16* Wg   = W   + (size_t)(m0 + arow0 + srow) * Kd + sch;
  const u16* Actg = Act + (size_t)(n0 + arow0 + srow) * Kd + sch;
  u16* Al = &lds.s.A[arow0 * 32];
  u16* Bl = &lds.s.B[arow0 * 32];
  f32x4 acc[4][4];
#pragma unroll
  for (int i = 0; i < 4; ++i)
#pragma unroll
    for (int j = 0; j < 4; ++j) acc[i][j] = (f32x4){0.f, 0.f, 0.f, 0.f};

  int ml = lane & 15, q8 = (lane >> 4) * 8;
  for (int k0 = 0; k0 < Kd; k0 += 32) {
    g2l16(Wg + k0, Al);
    g2l16(Wg + k0 + (size_t)16 * Kd, Al + 16 * 32);
    g2l16(Actg + k0, Bl);
    g2l16(Actg + k0 + (size_t)16 * Kd, Bl + 16 * 32);
    __syncthreads();
    bf16x8 af[4], bfr[4];
#pragma unroll
    for (int i = 0; i < 4; ++i) {
      af[i]  = *(const bf16x8*)&lds.s.A[(wm + i * 16 + ml) * 32 + q8];
      bfr[i] = *(const bf16x8*)&lds.s.B[(wn + i * 16 + ml) * 32 + q8];
    }
#pragma unroll
    for (int i = 0; i < 4; ++i)
#pragma unroll
      for (int j = 0; j < 4; ++j)
        acc[i][j] = __builtin_amdgcn_mfma_f32_16x16x32_bf16(af[i], bfr[j], acc[i][j], 0, 0, 0);
    __syncthreads();
  }

  if (mode == 0) {
    int q4 = (lane >> 4) * 4;
#pragma unroll
    for (int ph = 0; ph < 2; ++ph) {
      if (ph) __syncthreads();         // previous chunk's readers done
      if ((wv & 1) == ph) {            // waves whose wn == ph*64
#pragma unroll
        for (int i = 0; i < 4; ++i)
#pragma unroll
          for (int j = 0; j < 4; ++j) {
            int nl = j * 16 + ml;      // 0..63 local n
            int m = wm + i * 16 + q4;
            ushort4 o;
            o.x = f2bf(acc[i][j][0]); o.y = f2bf(acc[i][j][1]);
            o.z = f2bf(acc[i][j][2]); o.w = f2bf(acc[i][j][3]);
            *(ushort4*)&lds.T[nl * 132 + m] = o;
          }
      }
      __syncthreads();
#pragma unroll
      for (int it = 0; it < 4; ++it) {
        int nl = it * 16 + (tid >> 4);
        int mc = (tid & 15) * 8;
        ushort4 a = *(ushort4*)&lds.T[nl * 132 + mc];
        ushort4 b = *(ushort4*)&lds.T[nl * 132 + mc + 4];
        u16* gp = Cout + (size_t)(n0 + ph * 64 + nl) * Cstride + m0 + mc;
        *(ushort4*)gp = a;
        *(ushort4*)(gp + 4) = b;
      }
    }
  } else {
    int q4 = (lane >> 4) * 4;
#pragma unroll
    for (int i = 0; i < 4; ++i)
#pragma unroll
      for (int j = 0; j < 4; ++j) {
        int n = n0 + wn + j * 16 + ml;
        int bb = n / N_SP, p = n - bb * N_SP;
#pragma unroll
        for (int rr = 0; rr < 4; ++rr) {
          int m = m0 + wm + i * 16 + q4 + rr;
          Out[((size_t)bb * NDIM + m) * N_SP + p] = acc[i][j][rr] + bias[m];
        }
      }
  }
}

// ---------- ktv[bh][d][e] = sum_p k[p][d] v[p][e]  + fused diag & m0 ----------
__global__ __launch_bounds__(256) void ktv_kernel(
    const u16* __restrict__ KV, const u16* __restrict__ Q,
    float* __restrict__ ktv, float* __restrict__ dg, float* __restrict__ m0)
{
  int bh = blockIdx.y, bb = bh >> 3, hh = bh & 7;
  __shared__ float Ks[64][68];   // [pp][d]
  __shared__ float Vs[64][68];   // [pp][e]
  int tid = threadIdx.x, tx = tid & 15, ty = tid >> 4;
  float acc[4][4] = {{0.f}};
  float msum = 0.f;
  for (int ch = 0; ch < 7; ++ch) {
    int p0 = blockIdx.x * 448 + ch * 64;
    __syncthreads();
    for (int l = tid; l < 512; l += 256) {
      int pp = l >> 3, c8 = (l & 7) * 8;
      size_t rowp = (size_t)bb * N_SP + p0 + pp;
      const u16* krow = KV + rowp * (2 * NINNER) + hh * 64 + c8;
      const u16* qrow = Q + rowp * NINNER + hh * 64 + c8;
      ushort4 k1 = *(const ushort4*)krow, k2 = *(const ushort4*)(krow + 4);
      ushort4 v1 = *(const ushort4*)(krow + NINNER), v2 = *(const ushort4*)(krow + NINNER + 4);
      ushort4 q1 = *(const ushort4*)qrow, q2 = *(const ushort4*)(qrow + 4);
      float4 fk1 = {bf2f(k1.x), bf2f(k1.y), bf2f(k1.z), bf2f(k1.w)};
      float4 fk2 = {bf2f(k2.x), bf2f(k2.y), bf2f(k2.z), bf2f(k2.w)};
      float4 fv1 = {bf2f(v1.x), bf2f(v1.y), bf2f(v1.z), bf2f(v1.w)};
      float4 fv2 = {bf2f(v2.x), bf2f(v2.y), bf2f(v2.z), bf2f(v2.w)};
      *(float4*)&Ks[pp][c8] = fk1; *(float4*)&Ks[pp][c8 + 4] = fk2;
      *(float4*)&Vs[pp][c8] = fv1; *(float4*)&Vs[pp][c8 + 4] = fv2;
      float part = bf2f(q1.x) * fk1.x + bf2f(q1.y) * fk1.y
                 + bf2f(q1.z) * fk1.z + bf2f(q1.w) * fk1.w
                 + bf2f(q2.x) * fk2.x + bf2f(q2.y) * fk2.y
                 + bf2f(q2.z) * fk2.z + bf2f(q2.w) * fk2.w;
      part += __shfl_down(part, 4, 8);
      part += __shfl_down(part, 2, 8);
      part += __shfl_down(part, 1, 8);
      if ((tid & 7) == 0) {
        float dv = part * SCALE_F;
        dg[rowp * 8 + hh] = dv;
        msum += dv;
      }
    }
    __syncthreads();
#pragma unroll 4
    for (int pp = 0; pp < 64; ++pp) {
      float4 kk = *(const float4*)&Ks[pp][ty * 4];
      float4 vv = *(const float4*)&Vs[pp][tx * 4];
      const float* kkp = (const float*)&kk;
      const float* vvp = (const float*)&vv;
#pragma unroll
      for (int i = 0; i < 4; ++i)
#pragma unroll
        for (int j = 0; j < 4; ++j) acc[i][j] += kkp[i] * vvp[j];
    }
  }
  float* kt = ktv + bh * 4096;
#pragma unroll
  for (int i = 0; i < 4; ++i)
#pragma unroll
    for (int j = 0; j < 4; ++j)
      atomicAdd(&kt[(ty * 4 + i) * 64 + tx * 4 + j], acc[i][j]);
  // m0 block reduction
  float rsum = msum;
#pragma unroll
  for (int off = 32; off > 0; off >>= 1) rsum += __shfl_down(rsum, off);
  __shared__ float wsum[4];
  if ((tid & 63) == 0) wsum[tid >> 6] = rsum;
  __syncthreads();
  if (tid == 0) atomicAdd(m0, wsum[0] + wsum[1] + wsum[2] + wsum[3]);
}

// ---------- out[bn][e] = (m0 - diag)*v + SCALE * sum_d q[bn][d]*ktv[d][e] ----------
__global__ __launch_bounds__(256) void attn_out_kernel(
    const u16* __restrict__ Q, const u16* __restrict__ KV,
    const float* __restrict__ dg, const float* __restrict__ ktv,
    const float* __restrict__ m0p, u16* __restrict__ OutA)
{
  int bh = blockIdx.y, bb = bh >> 3, hh = bh & 7;
  int p0 = blockIdx.x * 64;
  __shared__ float Qs[64][68];   // [d][pp]  (transposed at stage)
  __shared__ float Kt[64][68];   // [d][e]
  __shared__ float Vs[64][68];   // [pp][e]
  __shared__ float ds_[64];
  int tid = threadIdx.x;
  const float* kt = ktv + bh * 4096;
  for (int l = tid; l < 4096; l += 256) Kt[l >> 6][l & 63] = kt[l];
  for (int l = tid; l < 512; l += 256) {
    int pp = l >> 3, c8 = (l & 7) * 8;
    const u16* qrow = Q + ((size_t)bb * N_SP + p0 + pp) * NINNER + hh * 64 + c8;
    ushort4 q1 = *(const ushort4*)qrow, q2 = *(const ushort4*)(qrow + 4);
    Qs[c8 + 0][pp] = bf2f(q1.x); Qs[c8 + 1][pp] = bf2f(q1.y);
    Qs[c8 + 2][pp] = bf2f(q1.z); Qs[c8 + 3][pp] = bf2f(q1.w);
    Qs[c8 + 4][pp] = bf2f(q2.x); Qs[c8 + 5][pp] = bf2f(q2.y);
    Qs[c8 + 6][pp] = bf2f(q2.z); Qs[c8 + 7][pp] = bf2f(q2.w);
    const u16* vrow = KV + ((size_t)bb * N_SP + p0 + pp) * (2 * NINNER) + NINNER + hh * 64 + c8;
    ushort4 v1 = *(const ushort4*)vrow, v2 = *(const ushort4*)(vrow + 4);
    float4 fv1 = {bf2f(v1.x), bf2f(v1.y), bf2f(v1.z), bf2f(v1.w)};
    float4 fv2 = {bf2f(v2.x), bf2f(v2.y), bf2f(v2.z), bf2f(v2.w)};
    *(float4*)&Vs[pp][c8] = fv1; *(float4*)&Vs[pp][c8 + 4] = fv2;
  }
  if (tid < 64) ds_[tid] = dg[((size_t)bb * N_SP + p0 + tid) * 8 + hh];
  __syncthreads();
  float m0v = *m0p;
  int tx = tid & 15, ty = tid >> 4;
  int e0 = tx * 4, pq = ty * 4;
  float acc[4][4] = {{0.f}};   // [pi][ej]
#pragma unroll 8
  for (int d = 0; d < 64; ++d) {
    float4 qv = *(const float4*)&Qs[d][pq];
    float4 kv4 = *(const float4*)&Kt[d][e0];
    const float* q_ = (const float*)&qv;
#pragma unroll
    for (int pi = 0; pi < 4; ++pi) {
      acc[pi][0] += q_[pi] * kv4.x;
      acc[pi][1] += q_[pi] * kv4.y;
      acc[pi][2] += q_[pi] * kv4.z;
      acc[pi][3] += q_[pi] * kv4.w;
    }
  }
#pragma unroll
  for (int pi = 0; pi < 4; ++pi) {
    float dv = m0v - ds_[pq + pi];
    ushort4 ov;
    ov.x = f2bf(SCALE_F * acc[pi][0] + dv * Vs[pq + pi][e0 + 0]);
    ov.y = f2bf(SCALE_F * acc[pi][1] + dv * Vs[pq + pi][e0 + 1]);
    ov.z = f2bf(SCALE_F * acc[pi][2] + dv * Vs[pq + pi][e0 + 2]);
    ov.w = f2bf(SCALE_F * acc[pi][3] + dv * Vs[pq + pi][e0 + 3]);
    *(ushort4*)(OutA + ((size_t)bb * N_SP + p0 + pq + pi) * NINNER + hh * 64 + e0) = ov;
  }
}

extern "C" void kernel_launch(void* const* d_in, const int* in_sizes, int n_in,
                              void* d_out, int out_size, void* d_ws, size_t ws_size,
                              hipStream_t stream)
{
  (void)in_sizes; (void)n_in; (void)out_size; (void)ws_size;
  const float* x      = (const float*)d_in[0];
  const float* wq_dw  = (const float*)d_in[1];
  const float* wq_g   = (const float*)d_in[2];
  const float* wq_b   = (const float*)d_in[3];
  const float* wq_m   = (const float*)d_in[4];
  const float* wq_v   = (const float*)d_in[5];
  const float* wq_pw  = (const float*)d_in[6];
  const float* wkv_dw = (const float*)d_in[7];
  const float* wkv_g  = (const float*)d_in[8];
  const float* wkv_b  = (const float*)d_in[9];
  const float* wkv_m  = (const float*)d_in[10];
  const float* wkv_v  = (const float*)d_in[11];
  const float* wkv_pw = (const float*)d_in[12];
  const float* wo     = (const float*)d_in[13];
  const float* bo     = (const float*)d_in[14];
  float* out = (float*)d_out;

  char* ws = (char*)d_ws;
  size_t off = 0;
  auto alloc = [&](size_t bytes) {
    void* p = ws + off; off = (off + bytes + 255) & ~(size_t)255; return p;
  };
  u16* yq   = (u16*)alloc((size_t)BNCOL * NDIM * 2);        // 19.27 MB  (BN, 384)
  u16* ykv  = (u16*)alloc((size_t)BNCOL * NDIM * 2);        // 19.27 MB
  u16* Qb   = (u16*)alloc((size_t)BNCOL * NINNER * 2);      // 25.69 MB  (BN, 512)
  u16* KVb  = (u16*)alloc((size_t)BNCOL * 2 * NINNER * 2);  // 51.38 MB  (BN, 1024)
  float* dgb  = (float*)alloc((size_t)BNCOL * 8 * 4);       // 0.80 MB   (bn, h)
  float* ktvb = (float*)alloc((size_t)64 * 4096 * 4 + 64);  // 1.05 MB (+m0 tail)
  u16* Wq  = (u16*)alloc((size_t)NINNER * NDIM * 2);        // 0.39 MB
  u16* Wkv = (u16*)alloc((size_t)2 * NINNER * NDIM * 2);    // 0.79 MB
  u16* Wo  = (u16*)alloc((size_t)NDIM * NINNER * 2);        // 0.39 MB
  float* fused = (float*)alloc((size_t)NDIM * 20 * 4);      // 30.7 KB BN-folded dw weights
  float* m0 = ktvb + 64 * 4096;
  u16* OutA = yq;   // alias: yq/ykv dead after the pw GEMMs; 25.7 MB fits in their 38.5 MB

  hipMemsetAsync(ktvb, 0, (size_t)64 * 4096 * 4 + 4, stream);

  cvt_kernel<<<1536, 256, 0, stream>>>(wq_pw, wkv_pw, wo, Wq, Wkv, Wo,
                                       wq_dw, wq_g, wq_b, wq_m, wq_v,
                                       wkv_dw, wkv_g, wkv_b, wkv_m, wkv_v, fused);

  dwbn_kernel<<<dim3(49, 12, 8), 256, 0, stream>>>(x, fused, yq, ykv);

  mfma_gemm<<<dim3(4 * 200), 256, 0, stream>>>(Wq, yq, NDIM, Qb, NINNER, 0, nullptr, nullptr, 4);
  mfma_gemm<<<dim3(8 * 200), 256, 0, stream>>>(Wkv, ykv, NDIM, KVb, 2 * NINNER, 0, nullptr, nullptr, 8);

  ktv_kernel<<<dim3(7, 64), 256, 0, stream>>>(KVb, Qb, ktvb, dgb, m0);
  attn_out_kernel<<<dim3(49, 64), 256, 0, stream>>>(Qb, KVb, dgb, ktvb, m0, OutA);

  mfma_gemm<<<dim3(3 * 200), 256, 0, stream>>>(Wo, OutA, NINNER, nullptr, 0, 1, bo, out, 3);
}

// Round 6
// 296.928 us; speedup vs baseline: 2.9712x; 1.0387x over previous
//
#include <hip/hip_runtime.h>

typedef unsigned short u16;

#define N_SP   3136     // 56*56
#define BNCOL  25088    // B * N_SP
#define NDIM   384
#define NINNER 512
#define SCALE_F 0.125f

typedef __attribute__((ext_vector_type(8))) short bf16x8;
typedef __attribute__((ext_vector_type(4))) float f32x4;

#define AS1 __attribute__((address_space(1)))
#define AS3 __attribute__((address_space(3)))

__device__ __forceinline__ float bf2f(u16 u) {
  union { unsigned int i; float f; } v; v.i = ((unsigned int)u) << 16; return v.f;
}
__device__ __forceinline__ u16 f2bf(float f) {
  union { float f; unsigned int i; } v; v.f = f;
  unsigned int r = v.i + 0x7fffu + ((v.i >> 16) & 1u);   // RNE
  return (u16)(r >> 16);
}

// async global->LDS, 16B per lane. lds base must be wave-uniform; lane i lands at lds + i*16B.
__device__ __forceinline__ void g2l16(const u16* g, u16* l) {
  __builtin_amdgcn_global_load_lds((const AS1 unsigned int*)g,
                                   (AS3 unsigned int*)l, 16, 0, 0);
}

// ---------- weight fp32 -> bf16 convert + BN-folded depthwise weights ----------
__global__ __launch_bounds__(256) void cvt_kernel(
    const float* __restrict__ a, const float* __restrict__ b, const float* __restrict__ c,
    u16* __restrict__ oa, u16* __restrict__ ob, u16* __restrict__ oc,
    const float* __restrict__ qdw, const float* __restrict__ qg, const float* __restrict__ qb2,
    const float* __restrict__ qm,  const float* __restrict__ qv,
    const float* __restrict__ kdw, const float* __restrict__ kg, const float* __restrict__ kb2,
    const float* __restrict__ km,  const float* __restrict__ kvv,
    float* __restrict__ fused)
{
  int i = blockIdx.x * 256 + threadIdx.x;
  if (i < 196608) oa[i] = f2bf(a[i]);
  ob[i] = f2bf(b[i]);               // grid sized exactly to 393216
  if (i < 196608) oc[i] = f2bf(c[i]);
  if (i < NDIM) {
    float invq = qg[i] * rsqrtf(qv[i] + 1e-5f);
    float invk = kg[i] * rsqrtf(kvv[i] + 1e-5f);
    float* f = fused + i * 20;
#pragma unroll
    for (int j = 0; j < 9; ++j) { f[j] = qdw[i*9+j] * invq; f[10+j] = kdw[i*9+j] * invk; }
    f[9]  = qb2[i] - qm[i] * invq;
    f[19] = kb2[i] - km[i] * invk;
  }
}

// ---------- fused depthwise 3x3 conv + BN (q and kv paths), output (BN, C) bf16 ----------
__global__ __launch_bounds__(256) void dwbn_kernel(
    const float* __restrict__ x, const float* __restrict__ fused,
    u16* __restrict__ yq, u16* __restrict__ ykv)
{
  __shared__ u16 Lq[64][40];
  __shared__ u16 Lk[64][40];
  int tid = threadIdx.x;
  int bb = blockIdx.z, c0 = blockIdx.y * 32, p0 = blockIdx.x * 64;
  int pl = tid & 63;
  int cg = __builtin_amdgcn_readfirstlane(tid >> 6);   // wave-uniform channel group
  int p = p0 + pl;
  int h = p / 56, w = p - h * 56;
  int roff[3], coff[3];
  float mr[3], mc[3];
#pragma unroll
  for (int d = 0; d < 3; ++d) {
    int r = h + d - 1;
    bool vr = (r >= 0) && (r < 56);
    roff[d] = (vr ? r : h) * 56;
    mr[d] = vr ? 1.f : 0.f;
    int cc = w + d - 1;
    bool vc = (cc >= 0) && (cc < 56);
    coff[d] = vc ? cc : w;
    mc[d] = vc ? 1.f : 0.f;
  }
  float m9[9];
#pragma unroll
  for (int dh = 0; dh < 3; ++dh)
#pragma unroll
    for (int dw = 0; dw < 3; ++dw) m9[dh*3+dw] = mr[dh] * mc[dw];

  __attribute__((aligned(16))) u16 oq[8], ok[8];
#pragma unroll
  for (int i = 0; i < 8; ++i) {
    int c = c0 + cg * 8 + i;
    const float* xp = x + ((size_t)bb * NDIM + c) * N_SP;
    const float* f = fused + c * 20;
    float v[9];
#pragma unroll
    for (int dh = 0; dh < 3; ++dh)
#pragma unroll
      for (int dw = 0; dw < 3; ++dw)
        v[dh*3+dw] = xp[roff[dh] + coff[dw]];
    float sq = f[9], sk = f[19];
#pragma unroll
    for (int j = 0; j < 9; ++j) {
      float xm = v[j] * m9[j];
      sq += xm * f[j];
      sk += xm * f[10+j];
    }
    oq[i] = f2bf(sq); ok[i] = f2bf(sk);
  }
  *(ushort4*)&Lq[pl][cg * 8]     = *(ushort4*)&oq[0];
  *(ushort4*)&Lq[pl][cg * 8 + 4] = *(ushort4*)&oq[4];
  *(ushort4*)&Lk[pl][cg * 8]     = *(ushort4*)&ok[0];
  *(ushort4*)&Lk[pl][cg * 8 + 4] = *(ushort4*)&ok[4];
  __syncthreads();
  int pr = tid >> 2, cc2 = (tid & 3) * 8;
  size_t g = ((size_t)bb * N_SP + p0 + pr) * NDIM + c0 + cc2;
  *(ushort4*)(yq + g)      = *(ushort4*)&Lq[pr][cc2];
  *(ushort4*)(yq + g + 4)  = *(ushort4*)&Lq[pr][cc2 + 4];
  *(ushort4*)(ykv + g)     = *(ushort4*)&Lk[pr][cc2];
  *(ushort4*)(ykv + g + 4) = *(ushort4*)&Lk[pr][cc2 + 4];
}

// ---------- MFMA GEMM: D[m][n] = sum_k A[m][k] * B[n][k]  (NT form) ----------
// mode 0: LDS-transpose, store bf16 rows of n: Cout[n][m] (stride Cstride).
// mode 1: +bias, fp32 NCHW scatter (m = channel, n = bn).
// Swizzle: Nt==8 -> nt=bid&7, mt=bid>>3 (swapped-operand KV GEMM). Else round-5 scheme.
__global__ __launch_bounds__(256) void mfma_gemm(
    const u16* __restrict__ A, const u16* __restrict__ B, int Kd,
    u16* __restrict__ Cout, int Cstride,
    int mode, const float* __restrict__ bias, float* __restrict__ Out, int Mt, int Nt)
{
  __shared__ union {
    struct { u16 A[128 * 32]; u16 B[128 * 32]; } s;   // [row][k] 8KB each
    u16 T[64 * 132];                                   // epilogue transpose chunk (16.9KB)
  } lds;
  int bid = blockIdx.x, mt, nt;
  if (Nt == 8) { nt = bid & 7; mt = bid >> 3; }
  else {
    int r = bid & 7, g = bid >> 3;
    mt = g % Mt; nt = (g / Mt) * 8 + r;
    if (nt >= Nt) return;
  }
  int m0 = mt * 128, n0 = nt * 128;

  int tid = threadIdx.x;
  int lane = tid & 63, wv = tid >> 6;
  int wm = (wv >> 1) * 64, wn = (wv & 1) * 64;
  int srow = lane >> 2;          // 0..15
  int sch = (lane & 3) * 8;      // k chunk
  int arow0 = wv * 32;           // each wave stages 32 rows of A and B
  const u16* Ag = A + (size_t)(m0 + arow0 + srow) * Kd + sch;
  const u16* Bg = B + (size_t)(n0 + arow0 + srow) * Kd + sch;
  u16* Al = &lds.s.A[arow0 * 32];
  u16* Bl = &lds.s.B[arow0 * 32];
  f32x4 acc[4][4];
#pragma unroll
  for (int i = 0; i < 4; ++i)
#pragma unroll
    for (int j = 0; j < 4; ++j) acc[i][j] = (f32x4){0.f, 0.f, 0.f, 0.f};

  int ml = lane & 15, q8 = (lane >> 4) * 8;
  for (int k0 = 0; k0 < Kd; k0 += 32) {
    g2l16(Ag + k0, Al);
    g2l16(Ag + k0 + (size_t)16 * Kd, Al + 16 * 32);
    g2l16(Bg + k0, Bl);
    g2l16(Bg + k0 + (size_t)16 * Kd, Bl + 16 * 32);
    __syncthreads();
    bf16x8 af[4], bfr[4];
#pragma unroll
    for (int i = 0; i < 4; ++i) {
      af[i]  = *(const bf16x8*)&lds.s.A[(wm + i * 16 + ml) * 32 + q8];
      bfr[i] = *(const bf16x8*)&lds.s.B[(wn + i * 16 + ml) * 32 + q8];
    }
#pragma unroll
    for (int i = 0; i < 4; ++i)
#pragma unroll
      for (int j = 0; j < 4; ++j)
        acc[i][j] = __builtin_amdgcn_mfma_f32_16x16x32_bf16(af[i], bfr[j], acc[i][j], 0, 0, 0);
    __syncthreads();
  }

  if (mode == 0) {
    int q4 = (lane >> 4) * 4;
#pragma unroll
    for (int ph = 0; ph < 2; ++ph) {
      if (ph) __syncthreads();         // previous chunk's readers done
      if ((wv & 1) == ph) {            // waves whose wn == ph*64
#pragma unroll
        for (int i = 0; i < 4; ++i)
#pragma unroll
          for (int j = 0; j < 4; ++j) {
            int nl = j * 16 + ml;      // 0..63 local n
            int m = wm + i * 16 + q4;
            ushort4 o;
            o.x = f2bf(acc[i][j][0]); o.y = f2bf(acc[i][j][1]);
            o.z = f2bf(acc[i][j][2]); o.w = f2bf(acc[i][j][3]);
            *(ushort4*)&lds.T[nl * 132 + m] = o;
          }
      }
      __syncthreads();
#pragma unroll
      for (int it = 0; it < 4; ++it) {
        int nl = it * 16 + (tid >> 4);
        int mc = (tid & 15) * 8;
        ushort4 a = *(ushort4*)&lds.T[nl * 132 + mc];
        ushort4 b = *(ushort4*)&lds.T[nl * 132 + mc + 4];
        u16* gp = Cout + (size_t)(n0 + ph * 64 + nl) * Cstride + m0 + mc;
        *(ushort4*)gp = a;
        *(ushort4*)(gp + 4) = b;
      }
    }
  } else {
    int q4 = (lane >> 4) * 4;
#pragma unroll
    for (int i = 0; i < 4; ++i)
#pragma unroll
      for (int j = 0; j < 4; ++j) {
        int n = n0 + wn + j * 16 + ml;
        int bb = n / N_SP, p = n - bb * N_SP;
#pragma unroll
        for (int rr = 0; rr < 4; ++rr) {
          int m = m0 + wm + i * 16 + q4 + rr;
          Out[((size_t)bb * NDIM + m) * N_SP + p] = acc[i][j][rr] + bias[m];
        }
      }
  }
}

// ---------- diag[bn][h] = SCALE * sum_d Q[bn][d] K[d][bn] ; m0 = sum ----------
// Q (bn,c), K (c,bn): K reads coalesced across lanes, Q rows per-lane (L2-friendly)
__global__ __launch_bounds__(256) void diag_kernel(
    const u16* __restrict__ Q, const u16* __restrict__ KV,
    float* __restrict__ dg, float* __restrict__ m0)
{
  int hh = blockIdx.y;
  int bn = blockIdx.x * 256 + threadIdx.x;
  const u16* qrow = Q + (size_t)bn * NINNER + hh * 64;
  const u16* kcol = KV + (size_t)(hh * 64) * BNCOL + bn;
  float s = 0.f;
#pragma unroll
  for (int d0 = 0; d0 < 64; d0 += 8) {
    ushort4 a = *(const ushort4*)(qrow + d0);
    ushort4 b = *(const ushort4*)(qrow + d0 + 4);
    const u16* kp = kcol + (size_t)d0 * BNCOL;
    s += bf2f(a.x) * bf2f(kp[0]);
    s += bf2f(a.y) * bf2f(kp[(size_t)1 * BNCOL]);
    s += bf2f(a.z) * bf2f(kp[(size_t)2 * BNCOL]);
    s += bf2f(a.w) * bf2f(kp[(size_t)3 * BNCOL]);
    s += bf2f(b.x) * bf2f(kp[(size_t)4 * BNCOL]);
    s += bf2f(b.y) * bf2f(kp[(size_t)5 * BNCOL]);
    s += bf2f(b.z) * bf2f(kp[(size_t)6 * BNCOL]);
    s += bf2f(b.w) * bf2f(kp[(size_t)7 * BNCOL]);
  }
  s *= SCALE_F;
  dg[(size_t)bn * 8 + hh] = s;
  float r = s;
#pragma unroll
  for (int off = 32; off > 0; off >>= 1) r += __shfl_down(r, off);
  __shared__ float wsum[4];
  if ((threadIdx.x & 63) == 0) wsum[threadIdx.x >> 6] = r;
  __syncthreads();
  if (threadIdx.x == 0) atomicAdd(m0, wsum[0] + wsum[1] + wsum[2] + wsum[3]);
}

// ---------- ktv[bh][d][e] = sum_p K[d][p] V[e][p]  (MFMA, frags direct from global) ----------
// grid (14, 64): wave w owns d-rows [16w,16w+16); no LDS, no barriers.
__global__ __launch_bounds__(256) void ktv_kernel(
    const u16* __restrict__ KV, float* __restrict__ ktv)
{
  int bh = blockIdx.y, bb = bh >> 3, hh = bh & 7;
  int tid = threadIdx.x;
  int w = tid >> 6, lane = tid & 63;
  int ml = lane & 15, quad = lane >> 4, q8 = quad * 8;
  size_t colbase = (size_t)bb * N_SP + blockIdx.x * 224 + q8;
  const u16* Ar = KV + (size_t)(hh * 64 + w * 16 + ml) * BNCOL + colbase;
  const u16* Br = KV + (size_t)(NINNER + hh * 64 + ml) * BNCOL + colbase;
  f32x4 acc[4];
#pragma unroll
  for (int j = 0; j < 4; ++j) acc[j] = (f32x4){0.f, 0.f, 0.f, 0.f};
#pragma unroll
  for (int t = 0; t < 7; ++t) {
    int po = t * 32;
    bf16x8 a = *(const bf16x8*)(Ar + po);
#pragma unroll
    for (int j = 0; j < 4; ++j) {
      bf16x8 b = *(const bf16x8*)(Br + (size_t)j * 16 * BNCOL + po);
      acc[j] = __builtin_amdgcn_mfma_f32_16x16x32_bf16(a, b, acc[j], 0, 0, 0);
    }
  }
  float* kt = ktv + bh * 4096;
#pragma unroll
  for (int j = 0; j < 4; ++j)
#pragma unroll
    for (int r = 0; r < 4; ++r)
      atomicAdd(&kt[(w * 16 + quad * 4 + r) * 64 + j * 16 + ml], acc[j][r]);
}

// ---------- out[p][e] = (m0 - diag[p])*V[e][p] + SCALE * sum_d Q[p][d]*ktv[d][e] ----------
// MFMA: A = Q rows (global), B = ktv^T bf16 (LDS). Output (bn, c) via LDS transpose.
__global__ __launch_bounds__(256) void attn_out_kernel(
    const u16* __restrict__ Q, const u16* __restrict__ KV,
    const float* __restrict__ dg, const float* __restrict__ ktv,
    const float* __restrict__ m0p, u16* __restrict__ OutA)
{
  __shared__ u16 Bt[64][72];    // ktv^T [e][d] bf16
  __shared__ u16 T2[64][72];    // out transpose [p][e]
  __shared__ float ds2[64];
  int bh = blockIdx.y, bb = bh >> 3, hh = bh & 7;
  int p0 = blockIdx.x * 64;
  int tid = threadIdx.x;
  const float* kt = ktv + bh * 4096;
  for (int l = tid; l < 4096; l += 256) {
    int d = l >> 6, e = l & 63;
    Bt[e][d] = f2bf(kt[l]);
  }
  if (tid < 64) ds2[tid] = dg[(size_t)(bb * N_SP + p0 + tid) * 8 + hh];
  __syncthreads();
  int w = tid >> 6, lane = tid & 63;
  int ml = lane & 15, quad = lane >> 4, q8 = quad * 8;
  const u16* Ar = Q + ((size_t)bb * N_SP + p0 + w * 16 + ml) * NINNER + hh * 64 + q8;
  bf16x8 a0 = *(const bf16x8*)Ar;
  bf16x8 a1 = *(const bf16x8*)(Ar + 32);
  f32x4 acc[4];
#pragma unroll
  for (int j = 0; j < 4; ++j) acc[j] = (f32x4){0.f, 0.f, 0.f, 0.f};
#pragma unroll
  for (int j = 0; j < 4; ++j) {
    bf16x8 b0 = *(const bf16x8*)&Bt[j * 16 + ml][q8];
    bf16x8 b1 = *(const bf16x8*)&Bt[j * 16 + ml][32 + q8];
    acc[j] = __builtin_amdgcn_mfma_f32_16x16x32_bf16(a0, b0, acc[j], 0, 0, 0);
    acc[j] = __builtin_amdgcn_mfma_f32_16x16x32_bf16(a1, b1, acc[j], 0, 0, 0);
  }
  float m0v = *m0p;
  size_t pcol = (size_t)bb * N_SP + p0 + w * 16 + quad * 4;
#pragma unroll
  for (int j = 0; j < 4; ++j) {
    const u16* vr = KV + (size_t)(NINNER + hh * 64 + j * 16 + ml) * BNCOL + pcol;
    ushort4 vv = *(const ushort4*)vr;
    const u16* vp = (const u16*)&vv;
#pragma unroll
    for (int r = 0; r < 4; ++r) {
      float dvm = m0v - ds2[w * 16 + quad * 4 + r];
      float o = SCALE_F * acc[j][r] + dvm * bf2f(vp[r]);
      T2[w * 16 + quad * 4 + r][j * 16 + ml] = f2bf(o);
    }
  }
  __syncthreads();
  int pl = tid >> 2, ec = (tid & 3) * 16;
  u16* gp = OutA + ((size_t)bb * N_SP + p0 + pl) * NINNER + hh * 64 + ec;
  *(ushort4*)gp        = *(ushort4*)&T2[pl][ec];
  *(ushort4*)(gp + 4)  = *(ushort4*)&T2[pl][ec + 4];
  *(ushort4*)(gp + 8)  = *(ushort4*)&T2[pl][ec + 8];
  *(ushort4*)(gp + 12) = *(ushort4*)&T2[pl][ec + 12];
}

extern "C" void kernel_launch(void* const* d_in, const int* in_sizes, int n_in,
                              void* d_out, int out_size, void* d_ws, size_t ws_size,
                              hipStream_t stream)
{
  (void)in_sizes; (void)n_in; (void)out_size; (void)ws_size;
  const float* x      = (const float*)d_in[0];
  const float* wq_dw  = (const float*)d_in[1];
  const float* wq_g   = (const float*)d_in[2];
  const float* wq_b   = (const float*)d_in[3];
  const float* wq_m   = (const float*)d_in[4];
  const float* wq_v   = (const float*)d_in[5];
  const float* wq_pw  = (const float*)d_in[6];
  const float* wkv_dw = (const float*)d_in[7];
  const float* wkv_g  = (const float*)d_in[8];
  const float* wkv_b  = (const float*)d_in[9];
  const float* wkv_m  = (const float*)d_in[10];
  const float* wkv_v  = (const float*)d_in[11];
  const float* wkv_pw = (const float*)d_in[12];
  const float* wo     = (const float*)d_in[13];
  const float* bo     = (const float*)d_in[14];
  float* out = (float*)d_out;

  char* ws = (char*)d_ws;
  size_t off = 0;
  auto alloc = [&](size_t bytes) {
    void* p = ws + off; off = (off + bytes + 255) & ~(size_t)255; return p;
  };
  u16* yq   = (u16*)alloc((size_t)BNCOL * NDIM * 2);        // 19.27 MB  (BN, 384)
  u16* ykv  = (u16*)alloc((size_t)BNCOL * NDIM * 2);        // 19.27 MB  (BN, 384)
  u16* Qb   = (u16*)alloc((size_t)BNCOL * NINNER * 2);      // 25.69 MB  (BN, 512)
  u16* KVb  = (u16*)alloc((size_t)2 * NINNER * BNCOL * 2);  // 51.38 MB  (1024, BN): K rows 0..511, V rows 512..1023
  float* dgb  = (float*)alloc((size_t)BNCOL * 8 * 4);       // 0.80 MB   (bn, h)
  float* ktvb = (float*)alloc((size_t)64 * 4096 * 4 + 64);  // 1.05 MB (+m0 tail)
  u16* Wq  = (u16*)alloc((size_t)NINNER * NDIM * 2);        // 0.39 MB
  u16* Wkv = (u16*)alloc((size_t)2 * NINNER * NDIM * 2);    // 0.79 MB
  u16* Wo  = (u16*)alloc((size_t)NDIM * NINNER * 2);        // 0.39 MB
  float* fused = (float*)alloc((size_t)NDIM * 20 * 4);      // 30.7 KB BN-folded dw weights
  float* m0 = ktvb + 64 * 4096;
  u16* OutA = yq;   // alias: yq/ykv dead after the pw GEMMs; 25.7 MB fits in their 38.5 MB

  hipMemsetAsync(ktvb, 0, (size_t)64 * 4096 * 4 + 4, stream);

  cvt_kernel<<<1536, 256, 0, stream>>>(wq_pw, wkv_pw, wo, Wq, Wkv, Wo,
                                       wq_dw, wq_g, wq_b, wq_m, wq_v,
                                       wkv_dw, wkv_g, wkv_b, wkv_m, wkv_v, fused);

  dwbn_kernel<<<dim3(49, 12, 8), 256, 0, stream>>>(x, fused, yq, ykv);

  // Q: A=Wq (4 m-tiles), B=yq (196 n-tiles) -> Qb (bn, 512)
  mfma_gemm<<<dim3(4 * 200), 256, 0, stream>>>(Wq, yq, NDIM, Qb, NINNER, 0, nullptr, nullptr, 4, 196);
  // KV swapped: A=ykv (196 m-tiles), B=Wkv (8 n-tiles) -> KVb (1024, bn)
  mfma_gemm<<<dim3(196 * 8), 256, 0, stream>>>(ykv, Wkv, NDIM, KVb, BNCOL, 0, nullptr, nullptr, 196, 8);

  diag_kernel<<<dim3(98, 8), 256, 0, stream>>>(Qb, KVb, dgb, m0);
  ktv_kernel<<<dim3(14, 64), 256, 0, stream>>>(KVb, ktvb);
  attn_out_kernel<<<dim3(49, 64), 256, 0, stream>>>(Qb, KVb, dgb, ktvb, m0, OutA);

  mfma_gemm<<<dim3(3 * 200), 256, 0, stream>>>(Wo, OutA, NINNER, nullptr, 0, 1, bo, out, 3, 196);
}